// Round 15
// baseline (576.792 us; speedup 1.0000x reference)
//
#include <hip/hip_runtime.h>
#include <hip/hip_bf16.h>
#include <cstdint>
#include <cstddef>

#define kN 50000
#define kE 800000
#define kC 2000

using s8v = __attribute__((ext_vector_type(8))) short;   // 8 bf16 (4 VGPRs) — MFMA A/B frag
using s4v = __attribute__((ext_vector_type(4))) short;
using f4v = __attribute__((ext_vector_type(4))) float;   // MFMA C/D frag

// cast-based bf16 convert -> compiler emits native v_cvt_pk_bf16_f32 pairs (T12/m240)
__device__ __forceinline__ short f2bf(float x){
  __hip_bfloat16 h = __float2bfloat16(x);
  return *reinterpret_cast<short*>(&h);
}
__device__ __forceinline__ float bf2f(short s){
  union { unsigned u; float f; } v; v.u = ((unsigned)(unsigned short)s) << 16;
  return v.f;
}

// ---------------- histogram: deg[dst], community counts ----------------
__global__ __launch_bounds__(256) void k_hist(const int* __restrict__ dst, int* __restrict__ deg,
                                              const int* __restrict__ community, int* __restrict__ ccnt){
  int i = blockIdx.x*256 + threadIdx.x;
  if (i < kE) atomicAdd(&deg[dst[i]], 1);
  if (i < kN) atomicAdd(&ccnt[community[i]], 1);
}

// ---------------- exclusive scan of deg -> offsets [kN+1], 4 elems/thread ----------------
__global__ __launch_bounds__(1024) void k_scan(const int* __restrict__ deg, int* __restrict__ offs){
  __shared__ int s_wsum[16];
  __shared__ int s_woff[17];
  __shared__ int s_carry;
  int t = threadIdx.x, lane = t & 63, w = t >> 6;
  if (t == 0) s_carry = 0;
  __syncthreads();
  for (int base = 0; base < kN; base += 4096){
    int i = base + t*4;
    int4 v = {0,0,0,0};
    if (i < kN) v = *reinterpret_cast<const int4*>(&deg[i]);   // kN % 4 == 0
    int s = v.x + v.y + v.z + v.w;
    int x = s;
    #pragma unroll
    for (int off = 1; off < 64; off <<= 1){
      int y = __shfl_up(x, off);
      if (lane >= off) x += y;
    }
    if (lane == 63) s_wsum[w] = x;
    __syncthreads();
    if (t == 0){
      int acc = 0;
      for (int q = 0; q < 16; q++){ s_woff[q] = acc; acc += s_wsum[q]; }
      s_woff[16] = acc;
    }
    __syncthreads();
    if (i < kN){
      int pre = s_carry + s_woff[w] + (x - s);
      int4 o; o.x = pre; o.y = pre + v.x; o.z = pre + v.x + v.y; o.w = pre + v.x + v.y + v.z;
      *reinterpret_cast<int4*>(&offs[i]) = o;
    }
    __syncthreads();
    if (t == 0) s_carry += s_woff[16];
    __syncthreads();
  }
  if (t == 0) offs[kN] = s_carry;   // == kE
}

// ---------------- exclusive scan of ccnt (kC=2000) -> coffs [kC+1], one pass ----------------
__global__ __launch_bounds__(512) void k_scan_c(const int* __restrict__ ccnt, int* __restrict__ coffs){
  __shared__ int s_wsum[8];
  __shared__ int s_woff[9];
  int t = threadIdx.x, lane = t & 63, w = t >> 6;
  int i = t*4;
  int4 v = {0,0,0,0};
  if (i < kC) v = *reinterpret_cast<const int4*>(&ccnt[i]);   // kC % 4 == 0
  int s = v.x + v.y + v.z + v.w;
  int x = s;
  #pragma unroll
  for (int off = 1; off < 64; off <<= 1){
    int y = __shfl_up(x, off);
    if (lane >= off) x += y;
  }
  if (lane == 63) s_wsum[w] = x;
  __syncthreads();
  if (t == 0){
    int a = 0;
    for (int q = 0; q < 8; q++){ s_woff[q] = a; a += s_wsum[q]; }
    s_woff[8] = a;
  }
  __syncthreads();
  if (i < kC){
    int pre = s_woff[w] + (x - s);
    int4 o; o.x = pre; o.y = pre + v.x; o.z = pre + v.x + v.y; o.w = pre + v.x + v.y + v.z;
    *reinterpret_cast<int4*>(&coffs[i]) = o;
  }
  if (t == 0) coffs[kC] = s_woff[8];   // == kN
}

// ---------------- place ids at atomic positions (order fixed later by k_sortseg) ----------------
__global__ __launch_bounds__(256) void k_place(const int* __restrict__ key, const int* __restrict__ offs,
                                               int* __restrict__ cursor, int* __restrict__ id_out, int nitems){
  int e = blockIdx.x*256 + threadIdx.x;
  if (e >= nitems) return;
  int d = key[e];
  int p = offs[d] + atomicAdd(&cursor[d], 1);
  id_out[p] = e;
}

// ---------------- deterministic segment sort: one wave per segment, ids ascending ----------------
__global__ __launch_bounds__(512) void k_sortseg(const int* __restrict__ offs, int nseg, int* __restrict__ ids){
  __shared__ int buf[8][256];
  int w = threadIdx.x >> 6, lane = threadIdx.x & 63;
  int seg = blockIdx.x*8 + w;
  if (seg >= nseg) return;
  int s0 = offs[seg], s1 = offs[seg+1];
  int len = s1 - s0;
  if (len <= 1 || len > 256) return;
  int* b = buf[w];
  for (int i = lane; i < len; i += 64) b[i] = ids[s0 + i];
  for (int i = lane; i < len; i += 64){
    int my = b[i];
    int r = 0;
    for (int j = 0; j < len; j++) r += (b[j] < my);
    ids[s0 + r] = my;
  }
}

// ---------------- build pos_of_edge + src_sorted from sorted eids (in place) ----------------
__global__ __launch_bounds__(256) void k_fill(const int* __restrict__ src,
                                              int* __restrict__ eid_then_src,
                                              int* __restrict__ pos_of_edge){
  int p = blockIdx.x*256 + threadIdx.x;
  if (p >= kE) return;
  int eid = eid_then_src[p];
  pos_of_edge[eid] = p;
  eid_then_src[p] = src[eid];
}

// ---------------- fused embed + A/B: x -> xe (VALU) -> h (MFMA) -> A,B (MFMA) ----------------
__global__ __launch_bounds__(512, 2) void k_embed_ab(
    const float* __restrict__ x,
    const float* __restrict__ W_e1, const float* __restrict__ b_e1,
    const float* __restrict__ W_e2, const float* __restrict__ b_e2,
    const float* __restrict__ W_e3, const float* __restrict__ b_e3,
    const float* __restrict__ W_src, const float* __restrict__ W_dst, const float* __restrict__ b_el,
    short* __restrict__ Hout, short* __restrict__ Aout, short* __restrict__ Bout, int ntiles)
{
  __shared__ short s_W[2][128][136];   // staging, reused as s_xe/s_h
  __shared__ float s_x[64][28];
  __shared__ float s_b3[128], s_bel[128];
  int tid = threadIdx.x;
  int lane = tid & 63, w = tid >> 6, lo = lane & 15, hi = lane >> 4;
  for (int idx = tid; idx < 128*128; idx += 512){
    int f = idx & 127, k = idx >> 7;
    s_W[0][f][k] = f2bf(W_e3[k*128 + f]);
    s_W[1][f][k] = f2bf(W_src[k*128 + f]);
  }
  if (tid < 128){ s_b3[tid] = b_e3[tid]; s_bel[tid] = b_el[tid]; }
  __syncthreads();
  s8v fe3[4], fsrc[4], fdst[4];
  #pragma unroll
  for (int ks = 0; ks < 4; ks++){
    fe3[ks]  = *(const s8v*)&s_W[0][w*16 + lo][ks*32 + hi*8];
    fsrc[ks] = *(const s8v*)&s_W[1][w*16 + lo][ks*32 + hi*8];
  }
  __syncthreads();
  for (int idx = tid; idx < 128*128; idx += 512){
    int f = idx & 127, k = idx >> 7;
    s_W[0][f][k] = f2bf(W_dst[k*128 + f]);
  }
  __syncthreads();
  #pragma unroll
  for (int ks = 0; ks < 4; ks++) fdst[ks] = *(const s8v*)&s_W[0][w*16 + lo][ks*32 + hi*8];

  short (*s_xe)[136] = s_W[0];
  short (*s_h)[136]  = s_W[1];

  for (int tile = blockIdx.x; tile < ntiles; tile += gridDim.x){
    int n0 = tile << 6;
    __syncthreads();
    for (int idx = tid; idx < 64*26; idx += 512){
      int nl = idx / 26, i = idx - nl*26; int n = n0 + nl;
      s_x[nl][i] = (n < kN) ? x[(size_t)n*26 + i] : 0.f;
    }
    __syncthreads();
    #pragma unroll
    for (int r = 0; r < 16; r++){
      int idx = (r << 9) + tid; int nl = idx >> 7, j = idx & 127;
      float a;
      if (j < 64){
        a = b_e1[j];
        #pragma unroll
        for (int i = 0; i < 14; i++) a += s_x[nl][i] * W_e1[i*64 + j];
      } else {
        int jj = j - 64;
        a = b_e2[jj];
        #pragma unroll
        for (int i = 0; i < 12; i++) a += s_x[nl][14 + i] * W_e2[i*64 + jj];
      }
      s_xe[nl][j] = f2bf(fmaxf(a, 0.f));
    }
    __syncthreads();
    #pragma unroll
    for (int et = 0; et < 4; et++){
      f4v acc = {0.f,0.f,0.f,0.f};
      #pragma unroll
      for (int ks = 0; ks < 4; ks++){
        s8v b = *(const s8v*)&s_xe[et*16 + lo][ks*32 + hi*8];
        acc = __builtin_amdgcn_mfma_f32_16x16x32_bf16(fe3[ks], b, acc, 0, 0, 0);
      }
      int n = n0 + et*16 + lo, f0 = w*16 + hi*4;
      s4v hv;
      #pragma unroll
      for (int j = 0; j < 4; j++) hv[j] = f2bf(fmaxf(acc[j] + s_b3[f0 + j], 0.f));
      *(s4v*)&s_h[et*16 + lo][f0] = hv;
      if (n < kN) *(s4v*)&Hout[(size_t)n*128 + f0] = hv;
    }
    __syncthreads();
    #pragma unroll
    for (int et = 0; et < 4; et++){
      f4v aA = {0.f,0.f,0.f,0.f}, aB = {0.f,0.f,0.f,0.f};
      #pragma unroll
      for (int ks = 0; ks < 4; ks++){
        s8v b = *(const s8v*)&s_h[et*16 + lo][ks*32 + hi*8];
        aA = __builtin_amdgcn_mfma_f32_16x16x32_bf16(fsrc[ks], b, aA, 0, 0, 0);
        aB = __builtin_amdgcn_mfma_f32_16x16x32_bf16(fdst[ks], b, aB, 0, 0, 0);
      }
      int n = n0 + et*16 + lo, f0 = w*16 + hi*4;
      if (n < kN){
        s4v Av, Bv;
        #pragma unroll
        for (int j = 0; j < 4; j++){ Av[j] = f2bf(aA[j] + s_bel[f0 + j]); Bv[j] = f2bf(aB[j]); }
        *(s4v*)&Aout[(size_t)n*128 + f0] = Av;
        *(s4v*)&Bout[(size_t)n*128 + f0] = Bv;
      }
    }
  }
}

// ---------------- per-edge kernel: FULLY MFMA (eemb too), 64 edges/tile, 8 waves ----------------
// Round 15: eemb = relu(ea@W_ee+b) computed by MFMA (K=8 zero-padded to 32, 1 inst per
// 16x16 tile; wave w -> M-tile w>>1, N-tiles (w&1)*2+{0,1}); bias A[src]+B[dst] gathered
// straight into s4v registers at loop top (consumed as GEMM1 acc init) — s_bias LDS and
// the scalar eemb loop are gone (~96 VALU inst/thread/tile saved). (512,4) no-spill point.
#define RO_EEMB 0        // short[64][72]  = 9216
#define RO_HE   9216     // short[64][136] = 17408 (end 26624)
#define RO_BM   26624    // float[128]     = 512 (end 27136)
#define KE_LDS  34816    // = W_m^T staging size (init reuse), > runtime 27136
__global__ __launch_bounds__(512, 4) void k_edge(
    const short* __restrict__ Abf, const short* __restrict__ Bbf,
    const float* __restrict__ edge_attr,
    const int* __restrict__ src, const int* __restrict__ dst,
    const int* __restrict__ posp,
    const float* __restrict__ W_ee, const float* __restrict__ b_ee,
    const float* __restrict__ W_ea, const float* __restrict__ W_m,
    const float* __restrict__ b_m,
    unsigned char* __restrict__ mask_out,
    int ntiles)
{
  __shared__ __align__(16) char smem[KE_LDS];
  short (*s_eemb)[72]  = (short(*)[72])(smem + RO_EEMB);
  short (*s_he)[136]   = (short(*)[136])(smem + RO_HE);
  float *s_bm  = (float*)(smem + RO_BM);

  int tid = threadIdx.x;
  const int lane = tid & 63, w = tid >> 6;
  const int lo = lane & 15, hi = lane >> 4;

  // stage W_ea -> a1 frags, then W_m -> a2 frags (same buffer region, sequential)
  s8v a1[2], a2[4];
  {
    short (*s_stg)[72] = (short(*)[72])smem;
    for (int idx = tid; idx < 128*64; idx += 512){ int f = idx & 127, k = idx >> 7; s_stg[f][k] = f2bf(W_ea[k*128+f]); }
    __syncthreads();
    #pragma unroll
    for (int ks = 0; ks < 2; ks++) a1[ks] = *(const s8v*)&s_stg[16*w + lo][ks*32 + hi*8];
    __syncthreads();
  }
  {
    short (*s_stg)[136] = (short(*)[136])smem;
    for (int idx = tid; idx < 128*128; idx += 512){ int f = idx & 127, k = idx >> 7; s_stg[f][k] = f2bf(W_m[k*128+f]); }
    __syncthreads();
    #pragma unroll
    for (int ks = 0; ks < 4; ks++) a2[ks] = *(const s8v*)&s_stg[16*w + lo][ks*32 + hi*8];
    __syncthreads();
  }
  if (tid >= 64 && tid < 192) s_bm[tid-64] = b_m[tid-64];

  // eemb MFMA constants: wave w computes M-tile mf=w>>1 (feats mf*16..+15),
  // N-tiles nt=(w&1)*2+{0,1} (edges nt*16..+15). A frag: k=hi*8+j (k<8 real, rest 0).
  const int mf = w >> 1;
  s8v ae = {0,0,0,0,0,0,0,0};
  if (hi == 0){
    #pragma unroll
    for (int j = 0; j < 8; j++) ae[j] = f2bf(W_ee[j*64 + mf*16 + lo]);
  }
  float bee4[4];
  #pragma unroll
  for (int j = 0; j < 4; j++) bee4[j] = b_ee[mf*16 + hi*4 + j];
  __syncthreads();   // s_bm + first-tile LDS reuse ordering

  const int f0 = 16*w + hi*4;

  for (int tile = blockIdx.x; tile < ntiles; tile += gridDim.x){
    int e0 = tile << 6;
    // issue bias gathers early (consumed at GEMM1 init; latency hides under eemb MFMA)
    s4v av[4], bv[4];
    #pragma unroll
    for (int et = 0; et < 4; et++){
      int e = e0 + et*16 + lo;
      int sr = src[e], dr = dst[e];
      av[et] = *(const s4v*)(Abf + (size_t)sr*128 + f0);
      bv[et] = *(const s4v*)(Bbf + (size_t)dr*128 + f0);
    }
    // eemb: 2 MFMA per wave (K=32, zero-padded from 8)
    #pragma unroll
    for (int q = 0; q < 2; q++){
      int nt = ((w & 1) << 1) + q;
      s8v be = {0,0,0,0,0,0,0,0};
      if (hi == 0){
        int eg = e0 + nt*16 + lo;
        float4 ea0 = *reinterpret_cast<const float4*>(&edge_attr[(size_t)eg*8]);
        float4 ea1 = *reinterpret_cast<const float4*>(&edge_attr[(size_t)eg*8 + 4]);
        be[0] = f2bf(ea0.x); be[1] = f2bf(ea0.y); be[2] = f2bf(ea0.z); be[3] = f2bf(ea0.w);
        be[4] = f2bf(ea1.x); be[5] = f2bf(ea1.y); be[6] = f2bf(ea1.z); be[7] = f2bf(ea1.w);
      }
      f4v ac = {0.f, 0.f, 0.f, 0.f};
      ac = __builtin_amdgcn_mfma_f32_16x16x32_bf16(ae, be, ac, 0, 0, 0);
      s4v ev;
      #pragma unroll
      for (int j = 0; j < 4; j++) ev[j] = f2bf(fmaxf(ac[j] + bee4[j], 0.f));
      *(s4v*)&s_eemb[nt*16 + lo][mf*16 + hi*4] = ev;
    }
    __syncthreads();                    // bar1: s_eemb ready
    // phase c: GEMM1 (K=64), acc init = A[src]+B[dst] from registers
    #pragma unroll
    for (int et = 0; et < 4; et++){
      int e = et*16 + lo;
      f4v acc;
      #pragma unroll
      for (int j = 0; j < 4; j++) acc[j] = bf2f(av[et][j]) + bf2f(bv[et][j]);
      #pragma unroll
      for (int ks = 0; ks < 2; ks++){
        s8v bfrag = *(const s8v*)&s_eemb[e][ks*32 + hi*8];
        acc = __builtin_amdgcn_mfma_f32_16x16x32_bf16(a1[ks], bfrag, acc, 0, 0, 0);
      }
      s4v hw;
      #pragma unroll
      for (int j = 0; j < 4; j++) hw[j] = f2bf(fmaxf(acc[j], 0.f));
      *(s4v*)&s_he[e][f0] = hw;
    }
    __syncthreads();                    // bar2: s_he ready
    // phase d: GEMM2 (K=128) -> fast-sigmoid -> packed u8 store
    #pragma unroll
    for (int et = 0; et < 4; et++){
      int e = et*16 + lo;
      int pe = posp[e0 + e];
      f4v acc = {0.f, 0.f, 0.f, 0.f};
      #pragma unroll
      for (int ks = 0; ks < 4; ks++){
        s8v bfrag = *(const s8v*)&s_he[e][ks*32 + hi*8];
        acc = __builtin_amdgcn_mfma_f32_16x16x32_bf16(a2[ks], bfrag, acc, 0, 0, 0);
      }
      unsigned pk = 0;
      #pragma unroll
      for (int j = 0; j < 4; j++){
        float ex = __expf(-(acc[j] + s_bm[f0 + j]));
        float m255 = __fdividef(255.f, 1.f + ex);
        pk |= (__float2uint_rn(m255) & 255u) << (j*8);
      }
      *reinterpret_cast<unsigned*>(&mask_out[(size_t)pe*128 + f0]) = pk;
    }
    __syncthreads();                    // loop-end: s_he/s_eemb safe for next tile
  }
}

// ---------------- fused conv layer: gather-aggregate + (agg@Wn + h@Wr) MFMA ----------------
__global__ __launch_bounds__(512, 6) void k_conv(
    const short* __restrict__ Hbf,
    const unsigned char* __restrict__ mask8,
    const int* __restrict__ src_sorted, const int* __restrict__ offs,
    const float* __restrict__ Wn, const float* __restrict__ Wr, const float* __restrict__ bc,
    short* __restrict__ Hout, float* __restrict__ Pout, int ntiles)
{
  __shared__ short s_buf[128][136];
  __shared__ float s_bc[128];
  int tid = threadIdx.x;
  int lane = tid & 63, w = tid >> 6, lo = lane & 15, hi = lane >> 4;
  s8v fn[4], fr[4];
  for (int idx = tid; idx < 128*128; idx += 512){
    int f = idx & 127, k = idx >> 7;
    s_buf[f][k] = f2bf(Wn[k*128 + f]);
  }
  if (tid < 128) s_bc[tid] = bc[tid];
  __syncthreads();
  #pragma unroll
  for (int ks = 0; ks < 4; ks++) fn[ks] = *(const s8v*)&s_buf[w*16 + lo][ks*32 + hi*8];
  __syncthreads();
  for (int idx = tid; idx < 128*128; idx += 512){
    int f = idx & 127, k = idx >> 7;
    s_buf[f][k] = f2bf(Wr[k*128 + f]);
  }
  __syncthreads();
  #pragma unroll
  for (int ks = 0; ks < 4; ks++) fr[ks] = *(const s8v*)&s_buf[w*16 + lo][ks*32 + hi*8];

  short (*s_agg)[136] = s_buf;        // rows 0..63
  short (*s_h)[136]   = s_buf + 64;   // rows 64..127
  const int nl8 = tid >> 3, p16 = (tid & 7) << 4;

  for (int tile = blockIdx.x; tile < ntiles; tile += gridDim.x){
    int n0 = tile << 6;
    __syncthreads();
    int n = n0 + nl8;
    {
      s8v h0 = {0,0,0,0,0,0,0,0}, h1 = {0,0,0,0,0,0,0,0};
      if (n < kN){
        h0 = *(const s8v*)&Hbf[(size_t)n*128 + p16];
        h1 = *(const s8v*)&Hbf[(size_t)n*128 + p16 + 8];
      }
      *(s8v*)&s_h[nl8][p16] = h0;
      *(s8v*)&s_h[nl8][p16 + 8] = h1;
    }
    float acc[16];
    #pragma unroll
    for (int q = 0; q < 16; q++) acc[q] = 0.f;
    int s0 = 0, s1 = 0;
    if (n < kN){ s0 = offs[n]; s1 = offs[n+1]; }
    int4 mv_c = {0,0,0,0}; s8v g0_c = {0,0,0,0,0,0,0,0}, g1_c = {0,0,0,0,0,0,0,0};
    if (s0 < s1){
      int sv = src_sorted[s0];
      mv_c = *reinterpret_cast<const int4*>(&mask8[(size_t)s0*128 + p16]);
      g0_c = *(const s8v*)&Hbf[(size_t)sv*128 + p16];
      g1_c = *(const s8v*)&Hbf[(size_t)sv*128 + p16 + 8];
    }
    for (int i = s0; i < s1; i++){
      int4 mv = mv_c; s8v g0 = g0_c, g1 = g1_c;
      if (i + 1 < s1){
        int svn = src_sorted[i + 1];
        mv_c = *reinterpret_cast<const int4*>(&mask8[(size_t)(i+1)*128 + p16]);
        g0_c = *(const s8v*)&Hbf[(size_t)svn*128 + p16];
        g1_c = *(const s8v*)&Hbf[(size_t)svn*128 + p16 + 8];
      }
      unsigned mw[4] = {(unsigned)mv.x, (unsigned)mv.y, (unsigned)mv.z, (unsigned)mv.w};
      float mf16[16];
      #pragma unroll
      for (int d = 0; d < 4; d++){
        mf16[d*4+0] = (float)( mw[d]        & 255u);
        mf16[d*4+1] = (float)((mw[d] >>  8) & 255u);
        mf16[d*4+2] = (float)((mw[d] >> 16) & 255u);
        mf16[d*4+3] = (float)( mw[d] >> 24       );
      }
      #pragma unroll
      for (int q = 0; q < 8; q++) acc[q]     += bf2f(g0[q]) * mf16[q];
      #pragma unroll
      for (int q = 0; q < 8; q++) acc[8 + q] += bf2f(g1[q]) * mf16[8 + q];
    }
    float inv = (1.f/255.f) * __fdividef(1.f, fmaxf((float)(s1 - s0), 1.f));
    {
      s8v a0, a1;
      #pragma unroll
      for (int q = 0; q < 8; q++){ a0[q] = f2bf(acc[q]*inv); a1[q] = f2bf(acc[8+q]*inv); }
      *(s8v*)&s_agg[nl8][p16] = a0;
      *(s8v*)&s_agg[nl8][p16 + 8] = a1;
    }
    __syncthreads();
    #pragma unroll
    for (int et = 0; et < 4; et++){
      f4v ac = {0.f,0.f,0.f,0.f};
      #pragma unroll
      for (int ks = 0; ks < 4; ks++){
        s8v bA = *(const s8v*)&s_agg[et*16 + lo][ks*32 + hi*8];
        ac = __builtin_amdgcn_mfma_f32_16x16x32_bf16(fn[ks], bA, ac, 0, 0, 0);
        s8v bH = *(const s8v*)&s_h[et*16 + lo][ks*32 + hi*8];
        ac = __builtin_amdgcn_mfma_f32_16x16x32_bf16(fr[ks], bH, ac, 0, 0, 0);
      }
      int nn = n0 + et*16 + lo, f0 = w*16 + hi*4;
      if (nn < kN){
        s4v hv; float4 pv;
        float v0 = fmaxf(ac[0] + s_bc[f0 + 0], 0.f);
        float v1 = fmaxf(ac[1] + s_bc[f0 + 1], 0.f);
        float v2 = fmaxf(ac[2] + s_bc[f0 + 2], 0.f);
        float v3 = fmaxf(ac[3] + s_bc[f0 + 3], 0.f);
        hv[0] = f2bf(v0); hv[1] = f2bf(v1); hv[2] = f2bf(v2); hv[3] = f2bf(v3);
        pv.x = v0; pv.y = v1; pv.z = v2; pv.w = v3;
        if (Hout) *(s4v*)&Hout[(size_t)nn*128 + f0] = hv;
        *reinterpret_cast<float4*>(&Pout[(size_t)nn*128 + f0]) = pv;
      }
    }
  }
}

// ---------------- final: community gather-pool (mean+max, no atomics) + MLP ----------------
__global__ __launch_bounds__(128) void k_final(
    const float* __restrict__ p1f, const float* __restrict__ p2f,
    const int* __restrict__ node_by_comm, const int* __restrict__ coffs,
    const float* __restrict__ W_l1, const float* __restrict__ b_l1,
    const float* __restrict__ W_l2, const float* __restrict__ b_l2,
    float* __restrict__ out)
{
  __shared__ float p[256];
  __shared__ float red[2];
  int c = blockIdx.x, t = threadIdx.x;
  int c0 = coffs[c], c1 = coffs[c+1];
  float s = 0.f, m1 = 0.f, m2 = 0.f;
  float v1_c = 0.f, v2_c = 0.f;
  if (c0 < c1){
    int n = node_by_comm[c0];
    v1_c = p1f[(size_t)n*128 + t];
    v2_c = p2f[(size_t)n*128 + t];
  }
  for (int i = c0; i < c1; i++){
    float v1 = v1_c, v2 = v2_c;
    if (i + 1 < c1){
      int nn = node_by_comm[i + 1];
      v1_c = p1f[(size_t)nn*128 + t];
      v2_c = p2f[(size_t)nn*128 + t];
    }
    s += v1 + v2;
    m1 = fmaxf(m1, v1);
    m2 = fmaxf(m2, v2);
  }
  float inv = 1.f / fmaxf((float)(c1 - c0), 1.f);
  p[t]       = s * inv;
  p[128 + t] = m1 + m2;
  __syncthreads();
  float acc = b_l1[t];
  for (int g = 0; g < 256; g++) acc += p[g]*W_l1[g*128+t];
  float hv = fmaxf(acc, 0.f) * W_l2[t];
  #pragma unroll
  for (int off = 32; off > 0; off >>= 1) hv += __shfl_down(hv, off);
  if ((t & 63) == 0) red[t>>6] = hv;
  __syncthreads();
  if (t == 0) out[c] = red[0] + red[1] + b_l2[0];
}

// diagnostic: surface ws_size through the absmax if workspace is too small
__global__ void k_diag(float* out, float v){
  int i = blockIdx.x*256 + threadIdx.x;
  if (i < kC) out[i] = v;
}

extern "C" void kernel_launch(void* const* d_in, const int* in_sizes, int n_in,
                              void* d_out, int out_size, void* d_ws, size_t ws_size,
                              hipStream_t stream)
{
  const float* x    = (const float*)d_in[0];
  const float* ea   = (const float*)d_in[1];
  const float* W_ee = (const float*)d_in[2];  const float* b_ee = (const float*)d_in[3];
  const float* W_e1 = (const float*)d_in[4];  const float* b_e1 = (const float*)d_in[5];
  const float* W_e2 = (const float*)d_in[6];  const float* b_e2 = (const float*)d_in[7];
  const float* W_e3 = (const float*)d_in[8];  const float* b_e3 = (const float*)d_in[9];
  const float* W_src= (const float*)d_in[10]; const float* W_dst= (const float*)d_in[11];
  const float* W_ea = (const float*)d_in[12]; const float* b_el = (const float*)d_in[13];
  const float* W_m  = (const float*)d_in[14]; const float* b_m  = (const float*)d_in[15];
  const float* W_n1 = (const float*)d_in[16]; const float* W_r1 = (const float*)d_in[17]; const float* b_c1 = (const float*)d_in[18];
  const float* W_n2 = (const float*)d_in[19]; const float* W_r2 = (const float*)d_in[20]; const float* b_c2 = (const float*)d_in[21];
  const float* W_l1 = (const float*)d_in[22]; const float* b_l1 = (const float*)d_in[23];
  const float* W_l2 = (const float*)d_in[24]; const float* b_l2 = (const float*)d_in[25];
  const int* eidx   = (const int*)d_in[26];
  const int* srcp   = eidx;
  const int* dstp   = eidx + kE;
  const int* community = (const int*)d_in[27];
  float* out = (float*)d_out;

  char* ws = (char*)d_ws;
  size_t off = 0;
  auto take = [&](size_t bytes)->char*{
    char* p = ws + off;
    off += (bytes + 511) & ~(size_t)511;
    return p;
  };
  const size_t NB2 = (size_t)kN*128*2;   // bf16 node buffer
  const size_t NB4 = (size_t)kN*128*4;   // fp32 node buffer
  short* hbuf  = (short*)take(NB2);
  short* h1buf = (short*)take(NB2);
  short* Abf16 = (short*)take(NB2);
  short* Bbf16 = (short*)take(NB2);
  float* p1f   = (float*)take(NB4);
  float* p2f   = (float*)take(NB4);
  char* z0 = ws + off;
  int* deg     = (int*)take((size_t)kN*4);
  int* cursor  = (int*)take((size_t)kN*4);
  int* ccnt    = (int*)take((size_t)kC*4);
  int* ccursor = (int*)take((size_t)kC*4);
  size_t zbytes = (size_t)((ws + off) - z0);
  int* offs    = (int*)take((size_t)(kN+1)*4);
  int* coffs   = (int*)take((size_t)(kC+1)*4);
  int* node_by_comm = (int*)take((size_t)kN*4);
  unsigned char* mask8 = (unsigned char*)take((size_t)kE*128);
  int* src_sorted  = (int*)take((size_t)kE*4);   // holds eids until k_fill, then src
  int* pos_of_edge = (int*)take((size_t)kE*4);
  size_t need = off;

  const int ntE   = (kE + 63) / 64;
  const int ntN64 = (kN + 63) / 64;

  if (ws_size >= need){
    hipMemsetAsync(z0, 0, zbytes, stream);
    k_hist    <<<(kE+255)/256, 256, 0, stream>>>(dstp, deg, community, ccnt);
    k_embed_ab<<<512, 512, 0, stream>>>(x, W_e1,b_e1, W_e2,b_e2, W_e3,b_e3,
                                        W_src, W_dst, b_el, hbuf, Abf16, Bbf16, ntN64);
    k_scan    <<<1, 1024, 0, stream>>>(deg, offs);
    k_scan_c  <<<1, 512, 0, stream>>>(ccnt, coffs);
    k_place   <<<(kE+255)/256, 256, 0, stream>>>(dstp, offs, cursor, src_sorted, kE);
    k_place   <<<(kN+255)/256, 256, 0, stream>>>(community, coffs, ccursor, node_by_comm, kN);
    k_sortseg <<<(kN+7)/8, 512, 0, stream>>>(offs, kN, src_sorted);
    k_sortseg <<<(kC+7)/8, 512, 0, stream>>>(coffs, kC, node_by_comm);
    k_fill    <<<(kE+255)/256, 256, 0, stream>>>(srcp, src_sorted, pos_of_edge);
    k_edge    <<<512, 512, 0, stream>>>(Abf16, Bbf16, ea, srcp, dstp, pos_of_edge,
                                        W_ee, b_ee, W_ea, W_m, b_m, mask8, ntE);
    k_conv    <<<ntN64, 512, 0, stream>>>(hbuf, mask8, src_sorted, offs,
                                          W_n1, W_r1, b_c1, h1buf, p1f, ntN64);
    k_conv    <<<ntN64, 512, 0, stream>>>(h1buf, mask8, src_sorted, offs,
                                          W_n2, W_r2, b_c2, nullptr, p2f, ntN64);
    k_final   <<<kC, 128, 0, stream>>>(p1f, p2f, node_by_comm, coffs,
                                       W_l1, b_l1, W_l2, b_l2, out);
  } else {
    k_diag<<<8, 256, 0, stream>>>(out, (float)(ws_size >> 20));
  }
}

// Round 16
// 530.090 us; speedup vs baseline: 1.0881x; 1.0881x over previous
//
#include <hip/hip_runtime.h>
#include <hip/hip_bf16.h>
#include <cstdint>
#include <cstddef>

#define kN 50000
#define kE 800000
#define kC 2000

using s8v = __attribute__((ext_vector_type(8))) short;   // 8 bf16 (4 VGPRs) — MFMA A/B frag
using s4v = __attribute__((ext_vector_type(4))) short;
using f4v = __attribute__((ext_vector_type(4))) float;   // MFMA C/D frag

// cast-based bf16 convert -> compiler emits native v_cvt_pk_bf16_f32 pairs (T12/m240)
__device__ __forceinline__ short f2bf(float x){
  __hip_bfloat16 h = __float2bfloat16(x);
  return *reinterpret_cast<short*>(&h);
}
__device__ __forceinline__ float bf2f(short s){
  union { unsigned u; float f; } v; v.u = ((unsigned)(unsigned short)s) << 16;
  return v.f;
}

// ---------------- histogram: deg[dst], community counts ----------------
__global__ __launch_bounds__(256) void k_hist(const int* __restrict__ dst, int* __restrict__ deg,
                                              const int* __restrict__ community, int* __restrict__ ccnt){
  int i = blockIdx.x*256 + threadIdx.x;
  if (i < kE) atomicAdd(&deg[dst[i]], 1);
  if (i < kN) atomicAdd(&ccnt[community[i]], 1);
}

// ---------------- exclusive scan of deg -> offsets [kN+1], 4 elems/thread ----------------
__global__ __launch_bounds__(1024) void k_scan(const int* __restrict__ deg, int* __restrict__ offs){
  __shared__ int s_wsum[16];
  __shared__ int s_woff[17];
  __shared__ int s_carry;
  int t = threadIdx.x, lane = t & 63, w = t >> 6;
  if (t == 0) s_carry = 0;
  __syncthreads();
  for (int base = 0; base < kN; base += 4096){
    int i = base + t*4;
    int4 v = {0,0,0,0};
    if (i < kN) v = *reinterpret_cast<const int4*>(&deg[i]);   // kN % 4 == 0
    int s = v.x + v.y + v.z + v.w;
    int x = s;
    #pragma unroll
    for (int off = 1; off < 64; off <<= 1){
      int y = __shfl_up(x, off);
      if (lane >= off) x += y;
    }
    if (lane == 63) s_wsum[w] = x;
    __syncthreads();
    if (t == 0){
      int acc = 0;
      for (int q = 0; q < 16; q++){ s_woff[q] = acc; acc += s_wsum[q]; }
      s_woff[16] = acc;
    }
    __syncthreads();
    if (i < kN){
      int pre = s_carry + s_woff[w] + (x - s);
      int4 o; o.x = pre; o.y = pre + v.x; o.z = pre + v.x + v.y; o.w = pre + v.x + v.y + v.z;
      *reinterpret_cast<int4*>(&offs[i]) = o;
    }
    __syncthreads();
    if (t == 0) s_carry += s_woff[16];
    __syncthreads();
  }
  if (t == 0) offs[kN] = s_carry;   // == kE
}

// ---------------- exclusive scan of ccnt (kC=2000) -> coffs [kC+1], one pass ----------------
__global__ __launch_bounds__(512) void k_scan_c(const int* __restrict__ ccnt, int* __restrict__ coffs){
  __shared__ int s_wsum[8];
  __shared__ int s_woff[9];
  int t = threadIdx.x, lane = t & 63, w = t >> 6;
  int i = t*4;
  int4 v = {0,0,0,0};
  if (i < kC) v = *reinterpret_cast<const int4*>(&ccnt[i]);   // kC % 4 == 0
  int s = v.x + v.y + v.z + v.w;
  int x = s;
  #pragma unroll
  for (int off = 1; off < 64; off <<= 1){
    int y = __shfl_up(x, off);
    if (lane >= off) x += y;
  }
  if (lane == 63) s_wsum[w] = x;
  __syncthreads();
  if (t == 0){
    int a = 0;
    for (int q = 0; q < 8; q++){ s_woff[q] = a; a += s_wsum[q]; }
    s_woff[8] = a;
  }
  __syncthreads();
  if (i < kC){
    int pre = s_woff[w] + (x - s);
    int4 o; o.x = pre; o.y = pre + v.x; o.z = pre + v.x + v.y; o.w = pre + v.x + v.y + v.z;
    *reinterpret_cast<int4*>(&coffs[i]) = o;
  }
  if (t == 0) coffs[kC] = s_woff[8];   // == kN
}

// ---------------- place ids at atomic positions (order fixed later by k_sortseg) ----------------
__global__ __launch_bounds__(256) void k_place(const int* __restrict__ key, const int* __restrict__ offs,
                                               int* __restrict__ cursor, int* __restrict__ id_out, int nitems){
  int e = blockIdx.x*256 + threadIdx.x;
  if (e >= nitems) return;
  int d = key[e];
  int p = offs[d] + atomicAdd(&cursor[d], 1);
  id_out[p] = e;
}

// ---------------- deterministic segment sort: one wave per segment, ids ascending ----------------
__global__ __launch_bounds__(512) void k_sortseg(const int* __restrict__ offs, int nseg, int* __restrict__ ids){
  __shared__ int buf[8][256];
  int w = threadIdx.x >> 6, lane = threadIdx.x & 63;
  int seg = blockIdx.x*8 + w;
  if (seg >= nseg) return;
  int s0 = offs[seg], s1 = offs[seg+1];
  int len = s1 - s0;
  if (len <= 1 || len > 256) return;
  int* b = buf[w];
  for (int i = lane; i < len; i += 64) b[i] = ids[s0 + i];
  for (int i = lane; i < len; i += 64){
    int my = b[i];
    int r = 0;
    for (int j = 0; j < len; j++) r += (b[j] < my);
    ids[s0 + r] = my;
  }
}

// ---------------- build pos_of_edge + src_sorted from sorted eids (in place) ----------------
__global__ __launch_bounds__(256) void k_fill(const int* __restrict__ src,
                                              int* __restrict__ eid_then_src,
                                              int* __restrict__ pos_of_edge){
  int p = blockIdx.x*256 + threadIdx.x;
  if (p >= kE) return;
  int eid = eid_then_src[p];
  pos_of_edge[eid] = p;
  eid_then_src[p] = src[eid];
}

// ---------------- fused embed + A/B: x -> xe (VALU) -> h (MFMA) -> A,B (MFMA) ----------------
__global__ __launch_bounds__(512, 2) void k_embed_ab(
    const float* __restrict__ x,
    const float* __restrict__ W_e1, const float* __restrict__ b_e1,
    const float* __restrict__ W_e2, const float* __restrict__ b_e2,
    const float* __restrict__ W_e3, const float* __restrict__ b_e3,
    const float* __restrict__ W_src, const float* __restrict__ W_dst, const float* __restrict__ b_el,
    short* __restrict__ Hout, short* __restrict__ Aout, short* __restrict__ Bout, int ntiles)
{
  __shared__ short s_W[2][128][136];   // staging, reused as s_xe/s_h
  __shared__ float s_x[64][28];
  __shared__ float s_b3[128], s_bel[128];
  int tid = threadIdx.x;
  int lane = tid & 63, w = tid >> 6, lo = lane & 15, hi = lane >> 4;
  for (int idx = tid; idx < 128*128; idx += 512){
    int f = idx & 127, k = idx >> 7;
    s_W[0][f][k] = f2bf(W_e3[k*128 + f]);
    s_W[1][f][k] = f2bf(W_src[k*128 + f]);
  }
  if (tid < 128){ s_b3[tid] = b_e3[tid]; s_bel[tid] = b_el[tid]; }
  __syncthreads();
  s8v fe3[4], fsrc[4], fdst[4];
  #pragma unroll
  for (int ks = 0; ks < 4; ks++){
    fe3[ks]  = *(const s8v*)&s_W[0][w*16 + lo][ks*32 + hi*8];
    fsrc[ks] = *(const s8v*)&s_W[1][w*16 + lo][ks*32 + hi*8];
  }
  __syncthreads();
  for (int idx = tid; idx < 128*128; idx += 512){
    int f = idx & 127, k = idx >> 7;
    s_W[0][f][k] = f2bf(W_dst[k*128 + f]);
  }
  __syncthreads();
  #pragma unroll
  for (int ks = 0; ks < 4; ks++) fdst[ks] = *(const s8v*)&s_W[0][w*16 + lo][ks*32 + hi*8];

  short (*s_xe)[136] = s_W[0];
  short (*s_h)[136]  = s_W[1];

  for (int tile = blockIdx.x; tile < ntiles; tile += gridDim.x){
    int n0 = tile << 6;
    __syncthreads();
    for (int idx = tid; idx < 64*26; idx += 512){
      int nl = idx / 26, i = idx - nl*26; int n = n0 + nl;
      s_x[nl][i] = (n < kN) ? x[(size_t)n*26 + i] : 0.f;
    }
    __syncthreads();
    #pragma unroll
    for (int r = 0; r < 16; r++){
      int idx = (r << 9) + tid; int nl = idx >> 7, j = idx & 127;
      float a;
      if (j < 64){
        a = b_e1[j];
        #pragma unroll
        for (int i = 0; i < 14; i++) a += s_x[nl][i] * W_e1[i*64 + j];
      } else {
        int jj = j - 64;
        a = b_e2[jj];
        #pragma unroll
        for (int i = 0; i < 12; i++) a += s_x[nl][14 + i] * W_e2[i*64 + jj];
      }
      s_xe[nl][j] = f2bf(fmaxf(a, 0.f));
    }
    __syncthreads();
    #pragma unroll
    for (int et = 0; et < 4; et++){
      f4v acc = {0.f,0.f,0.f,0.f};
      #pragma unroll
      for (int ks = 0; ks < 4; ks++){
        s8v b = *(const s8v*)&s_xe[et*16 + lo][ks*32 + hi*8];
        acc = __builtin_amdgcn_mfma_f32_16x16x32_bf16(fe3[ks], b, acc, 0, 0, 0);
      }
      int n = n0 + et*16 + lo, f0 = w*16 + hi*4;
      s4v hv;
      #pragma unroll
      for (int j = 0; j < 4; j++) hv[j] = f2bf(fmaxf(acc[j] + s_b3[f0 + j], 0.f));
      *(s4v*)&s_h[et*16 + lo][f0] = hv;
      if (n < kN) *(s4v*)&Hout[(size_t)n*128 + f0] = hv;
    }
    __syncthreads();
    #pragma unroll
    for (int et = 0; et < 4; et++){
      f4v aA = {0.f,0.f,0.f,0.f}, aB = {0.f,0.f,0.f,0.f};
      #pragma unroll
      for (int ks = 0; ks < 4; ks++){
        s8v b = *(const s8v*)&s_h[et*16 + lo][ks*32 + hi*8];
        aA = __builtin_amdgcn_mfma_f32_16x16x32_bf16(fsrc[ks], b, aA, 0, 0, 0);
        aB = __builtin_amdgcn_mfma_f32_16x16x32_bf16(fdst[ks], b, aB, 0, 0, 0);
      }
      int n = n0 + et*16 + lo, f0 = w*16 + hi*4;
      if (n < kN){
        s4v Av, Bv;
        #pragma unroll
        for (int j = 0; j < 4; j++){ Av[j] = f2bf(aA[j] + s_bel[f0 + j]); Bv[j] = f2bf(aB[j]); }
        *(s4v*)&Aout[(size_t)n*128 + f0] = Av;
        *(s4v*)&Bout[(size_t)n*128 + f0] = Bv;
      }
    }
  }
}

// ---------------- per-edge kernel: MFMA bf16, 64 edges/tile, 8 waves (round-14 proven) ----------------
// Scalar eemb kept deliberately: its 64 FMAs hide the A/B gather latency (round-15
// lesson — MFMA-izing it exposed the latency and cost +44 µs). (512,4) no-spill point.
#define RO_EEMB 0        // short[64][72]  = 9216
#define RO_HE   9216     // short[64][136] = 17408 (end 26624)
#define RO_BIAS 26624    // short[64][136] = 17408 (end 44032)
#define RO_WEE  44032    // float[512]     = 2048
#define RO_BEE  46080    // float[64]      = 256
#define RO_BM   46336    // float[128]     = 512 (end 46848)
#define KE_LDS  46848
__global__ __launch_bounds__(512, 4) void k_edge(
    const short* __restrict__ Abf, const short* __restrict__ Bbf,
    const float* __restrict__ edge_attr,
    const int* __restrict__ src, const int* __restrict__ dst,
    const int* __restrict__ posp,
    const float* __restrict__ W_ee, const float* __restrict__ b_ee,
    const float* __restrict__ W_ea, const float* __restrict__ W_m,
    const float* __restrict__ b_m,
    unsigned char* __restrict__ mask_out,
    int ntiles)
{
  __shared__ __align__(16) char smem[KE_LDS];
  short (*s_eemb)[72]  = (short(*)[72])(smem + RO_EEMB);
  short (*s_he)[136]   = (short(*)[136])(smem + RO_HE);
  short (*s_bias)[136] = (short(*)[136])(smem + RO_BIAS);
  float *s_Wee = (float*)(smem + RO_WEE);
  float *s_bee = (float*)(smem + RO_BEE);
  float *s_bm  = (float*)(smem + RO_BM);

  int tid = threadIdx.x;
  const int lane = tid & 63, w = tid >> 6;
  const int lo = lane & 15, hi = lane >> 4;

  s8v a1[2], a2[4];
  {
    short (*s_stg)[72] = (short(*)[72])smem;
    for (int idx = tid; idx < 128*64; idx += 512){ int f = idx & 127, k = idx >> 7; s_stg[f][k] = f2bf(W_ea[k*128+f]); }
    __syncthreads();
    #pragma unroll
    for (int ks = 0; ks < 2; ks++) a1[ks] = *(const s8v*)&s_stg[16*w + lo][ks*32 + hi*8];
    __syncthreads();
  }
  {
    short (*s_stg)[136] = (short(*)[136])smem;
    for (int idx = tid; idx < 128*128; idx += 512){ int f = idx & 127, k = idx >> 7; s_stg[f][k] = f2bf(W_m[k*128+f]); }
    __syncthreads();
    #pragma unroll
    for (int ks = 0; ks < 4; ks++) a2[ks] = *(const s8v*)&s_stg[16*w + lo][ks*32 + hi*8];
    __syncthreads();
  }
  s_Wee[tid] = W_ee[tid];
  if (tid < 64) s_bee[tid] = b_ee[tid];
  if (tid >= 64 && tid < 192) s_bm[tid-64] = b_m[tid-64];
  __syncthreads();

  const int el8 = tid >> 3, kb = (tid & 7) << 3;
  const int p16 = (tid & 7) << 4;
  const int f0 = 16*w + hi*4;

  for (int tile = blockIdx.x; tile < ntiles; tile += gridDim.x){
    int e0 = tile << 6;
    // phase b: direct per-thread loads (edge el8), A/B gathers + eemb + bias
    {
      int eg = e0 + el8;
      int sr = src[eg], dr = dst[eg];
      float4 ea0 = *reinterpret_cast<const float4*>(&edge_attr[(size_t)eg*8]);
      float4 ea1 = *reinterpret_cast<const float4*>(&edge_attr[(size_t)eg*8 + 4]);
      int sb = sr*128 + p16, db = dr*128 + p16;
      s8v av0 = *(const s8v*)(Abf + sb);
      s8v av1 = *(const s8v*)(Abf + sb + 8);
      s8v bv0 = *(const s8v*)(Bbf + db);
      s8v bv1 = *(const s8v*)(Bbf + db + 8);
      float eav[8] = {ea0.x, ea0.y, ea0.z, ea0.w, ea1.x, ea1.y, ea1.z, ea1.w};
      float ee_[8];
      #pragma unroll
      for (int j = 0; j < 8; j++){
        float acc = s_bee[kb + j];
        #pragma unroll
        for (int i = 0; i < 8; i++) acc += eav[i] * s_Wee[i*64 + kb + j];
        ee_[j] = fmaxf(acc, 0.f);
      }
      s8v ep;
      #pragma unroll
      for (int j = 0; j < 8; j++) ep[j] = f2bf(ee_[j]);
      *(s8v*)&s_eemb[el8][kb] = ep;
      s8v b0, b1;
      #pragma unroll
      for (int q = 0; q < 8; q++){
        b0[q] = f2bf(bf2f(av0[q]) + bf2f(bv0[q]));
        b1[q] = f2bf(bf2f(av1[q]) + bf2f(bv1[q]));
      }
      *(s8v*)&s_bias[el8][p16]     = b0;
      *(s8v*)&s_bias[el8][p16 + 8] = b1;
    }
    __syncthreads();
    // phase c: GEMM1 (K=64), acc init = bias
    #pragma unroll
    for (int et = 0; et < 4; et++){
      int e = et*16 + lo;
      s4v bb = *(const s4v*)&s_bias[e][f0];
      f4v acc;
      #pragma unroll
      for (int j = 0; j < 4; j++) acc[j] = bf2f(bb[j]);
      #pragma unroll
      for (int ks = 0; ks < 2; ks++){
        s8v bfrag = *(const s8v*)&s_eemb[e][ks*32 + hi*8];
        acc = __builtin_amdgcn_mfma_f32_16x16x32_bf16(a1[ks], bfrag, acc, 0, 0, 0);
      }
      s4v hw;
      #pragma unroll
      for (int j = 0; j < 4; j++) hw[j] = f2bf(fmaxf(acc[j], 0.f));
      *(s4v*)&s_he[e][f0] = hw;
    }
    __syncthreads();
    // phase d: GEMM2 (K=128) -> fast-sigmoid -> packed u8 store
    #pragma unroll
    for (int et = 0; et < 4; et++){
      int e = et*16 + lo;
      int pe = posp[e0 + e];
      f4v acc = {0.f, 0.f, 0.f, 0.f};
      #pragma unroll
      for (int ks = 0; ks < 4; ks++){
        s8v bfrag = *(const s8v*)&s_he[e][ks*32 + hi*8];
        acc = __builtin_amdgcn_mfma_f32_16x16x32_bf16(a2[ks], bfrag, acc, 0, 0, 0);
      }
      unsigned pk = 0;
      #pragma unroll
      for (int j = 0; j < 4; j++){
        float ex = __expf(-(acc[j] + s_bm[f0 + j]));
        float m255 = __fdividef(255.f, 1.f + ex);
        pk |= (__float2uint_rn(m255) & 255u) << (j*8);
      }
      *reinterpret_cast<unsigned*>(&mask_out[(size_t)pe*128 + f0]) = pk;
    }
    __syncthreads();
  }
}

// ---------------- fused conv layer: gather-aggregate + (agg@Wn + h@Wr) MFMA ----------------
__global__ __launch_bounds__(512, 6) void k_conv(
    const short* __restrict__ Hbf,
    const unsigned char* __restrict__ mask8,
    const int* __restrict__ src_sorted, const int* __restrict__ offs,
    const float* __restrict__ Wn, const float* __restrict__ Wr, const float* __restrict__ bc,
    short* __restrict__ Hout, float* __restrict__ Pout, int ntiles)
{
  __shared__ short s_buf[128][136];
  __shared__ float s_bc[128];
  int tid = threadIdx.x;
  int lane = tid & 63, w = tid >> 6, lo = lane & 15, hi = lane >> 4;
  s8v fn[4], fr[4];
  for (int idx = tid; idx < 128*128; idx += 512){
    int f = idx & 127, k = idx >> 7;
    s_buf[f][k] = f2bf(Wn[k*128 + f]);
  }
  if (tid < 128) s_bc[tid] = bc[tid];
  __syncthreads();
  #pragma unroll
  for (int ks = 0; ks < 4; ks++) fn[ks] = *(const s8v*)&s_buf[w*16 + lo][ks*32 + hi*8];
  __syncthreads();
  for (int idx = tid; idx < 128*128; idx += 512){
    int f = idx & 127, k = idx >> 7;
    s_buf[f][k] = f2bf(Wr[k*128 + f]);
  }
  __syncthreads();
  #pragma unroll
  for (int ks = 0; ks < 4; ks++) fr[ks] = *(const s8v*)&s_buf[w*16 + lo][ks*32 + hi*8];

  short (*s_agg)[136] = s_buf;        // rows 0..63
  short (*s_h)[136]   = s_buf + 64;   // rows 64..127
  const int nl8 = tid >> 3, p16 = (tid & 7) << 4;

  for (int tile = blockIdx.x; tile < ntiles; tile += gridDim.x){
    int n0 = tile << 6;
    __syncthreads();
    int n = n0 + nl8;
    {
      s8v h0 = {0,0,0,0,0,0,0,0}, h1 = {0,0,0,0,0,0,0,0};
      if (n < kN){
        h0 = *(const s8v*)&Hbf[(size_t)n*128 + p16];
        h1 = *(const s8v*)&Hbf[(size_t)n*128 + p16 + 8];
      }
      *(s8v*)&s_h[nl8][p16] = h0;
      *(s8v*)&s_h[nl8][p16 + 8] = h1;
    }
    float acc[16];
    #pragma unroll
    for (int q = 0; q < 16; q++) acc[q] = 0.f;
    int s0 = 0, s1 = 0;
    if (n < kN){ s0 = offs[n]; s1 = offs[n+1]; }
    int4 mv_c = {0,0,0,0}; s8v g0_c = {0,0,0,0,0,0,0,0}, g1_c = {0,0,0,0,0,0,0,0};
    if (s0 < s1){
      int sv = src_sorted[s0];
      mv_c = *reinterpret_cast<const int4*>(&mask8[(size_t)s0*128 + p16]);
      g0_c = *(const s8v*)&Hbf[(size_t)sv*128 + p16];
      g1_c = *(const s8v*)&Hbf[(size_t)sv*128 + p16 + 8];
    }
    for (int i = s0; i < s1; i++){
      int4 mv = mv_c; s8v g0 = g0_c, g1 = g1_c;
      if (i + 1 < s1){
        int svn = src_sorted[i + 1];
        mv_c = *reinterpret_cast<const int4*>(&mask8[(size_t)(i+1)*128 + p16]);
        g0_c = *(const s8v*)&Hbf[(size_t)svn*128 + p16];
        g1_c = *(const s8v*)&Hbf[(size_t)svn*128 + p16 + 8];
      }
      unsigned mw[4] = {(unsigned)mv.x, (unsigned)mv.y, (unsigned)mv.z, (unsigned)mv.w};
      float mf16[16];
      #pragma unroll
      for (int d = 0; d < 4; d++){
        mf16[d*4+0] = (float)( mw[d]        & 255u);
        mf16[d*4+1] = (float)((mw[d] >>  8) & 255u);
        mf16[d*4+2] = (float)((mw[d] >> 16) & 255u);
        mf16[d*4+3] = (float)( mw[d] >> 24       );
      }
      #pragma unroll
      for (int q = 0; q < 8; q++) acc[q]     += bf2f(g0[q]) * mf16[q];
      #pragma unroll
      for (int q = 0; q < 8; q++) acc[8 + q] += bf2f(g1[q]) * mf16[8 + q];
    }
    float inv = (1.f/255.f) * __fdividef(1.f, fmaxf((float)(s1 - s0), 1.f));
    {
      s8v a0, a1;
      #pragma unroll
      for (int q = 0; q < 8; q++){ a0[q] = f2bf(acc[q]*inv); a1[q] = f2bf(acc[8+q]*inv); }
      *(s8v*)&s_agg[nl8][p16] = a0;
      *(s8v*)&s_agg[nl8][p16 + 8] = a1;
    }
    __syncthreads();
    #pragma unroll
    for (int et = 0; et < 4; et++){
      f4v ac = {0.f,0.f,0.f,0.f};
      #pragma unroll
      for (int ks = 0; ks < 4; ks++){
        s8v bA = *(const s8v*)&s_agg[et*16 + lo][ks*32 + hi*8];
        ac = __builtin_amdgcn_mfma_f32_16x16x32_bf16(fn[ks], bA, ac, 0, 0, 0);
        s8v bH = *(const s8v*)&s_h[et*16 + lo][ks*32 + hi*8];
        ac = __builtin_amdgcn_mfma_f32_16x16x32_bf16(fr[ks], bH, ac, 0, 0, 0);
      }
      int nn = n0 + et*16 + lo, f0 = w*16 + hi*4;
      if (nn < kN){
        s4v hv; float4 pv;
        float v0 = fmaxf(ac[0] + s_bc[f0 + 0], 0.f);
        float v1 = fmaxf(ac[1] + s_bc[f0 + 1], 0.f);
        float v2 = fmaxf(ac[2] + s_bc[f0 + 2], 0.f);
        float v3 = fmaxf(ac[3] + s_bc[f0 + 3], 0.f);
        hv[0] = f2bf(v0); hv[1] = f2bf(v1); hv[2] = f2bf(v2); hv[3] = f2bf(v3);
        pv.x = v0; pv.y = v1; pv.z = v2; pv.w = v3;
        if (Hout) *(s4v*)&Hout[(size_t)nn*128 + f0] = hv;
        *reinterpret_cast<float4*>(&Pout[(size_t)nn*128 + f0]) = pv;
      }
    }
  }
}

// ---------------- final: community gather-pool (mean+max, no atomics) + MLP ----------------
__global__ __launch_bounds__(128) void k_final(
    const float* __restrict__ p1f, const float* __restrict__ p2f,
    const int* __restrict__ node_by_comm, const int* __restrict__ coffs,
    const float* __restrict__ W_l1, const float* __restrict__ b_l1,
    const float* __restrict__ W_l2, const float* __restrict__ b_l2,
    float* __restrict__ out)
{
  __shared__ float p[256];
  __shared__ float red[2];
  int c = blockIdx.x, t = threadIdx.x;
  int c0 = coffs[c], c1 = coffs[c+1];
  float s = 0.f, m1 = 0.f, m2 = 0.f;
  float v1_c = 0.f, v2_c = 0.f;
  if (c0 < c1){
    int n = node_by_comm[c0];
    v1_c = p1f[(size_t)n*128 + t];
    v2_c = p2f[(size_t)n*128 + t];
  }
  for (int i = c0; i < c1; i++){
    float v1 = v1_c, v2 = v2_c;
    if (i + 1 < c1){
      int nn = node_by_comm[i + 1];
      v1_c = p1f[(size_t)nn*128 + t];
      v2_c = p2f[(size_t)nn*128 + t];
    }
    s += v1 + v2;
    m1 = fmaxf(m1, v1);
    m2 = fmaxf(m2, v2);
  }
  float inv = 1.f / fmaxf((float)(c1 - c0), 1.f);
  p[t]       = s * inv;
  p[128 + t] = m1 + m2;
  __syncthreads();
  float acc = b_l1[t];
  for (int g = 0; g < 256; g++) acc += p[g]*W_l1[g*128+t];
  float hv = fmaxf(acc, 0.f) * W_l2[t];
  #pragma unroll
  for (int off = 32; off > 0; off >>= 1) hv += __shfl_down(hv, off);
  if ((t & 63) == 0) red[t>>6] = hv;
  __syncthreads();
  if (t == 0) out[c] = red[0] + red[1] + b_l2[0];
}

// diagnostic: surface ws_size through the absmax if workspace is too small
__global__ void k_diag(float* out, float v){
  int i = blockIdx.x*256 + threadIdx.x;
  if (i < kC) out[i] = v;
}

extern "C" void kernel_launch(void* const* d_in, const int* in_sizes, int n_in,
                              void* d_out, int out_size, void* d_ws, size_t ws_size,
                              hipStream_t stream)
{
  const float* x    = (const float*)d_in[0];
  const float* ea   = (const float*)d_in[1];
  const float* W_ee = (const float*)d_in[2];  const float* b_ee = (const float*)d_in[3];
  const float* W_e1 = (const float*)d_in[4];  const float* b_e1 = (const float*)d_in[5];
  const float* W_e2 = (const float*)d_in[6];  const float* b_e2 = (const float*)d_in[7];
  const float* W_e3 = (const float*)d_in[8];  const float* b_e3 = (const float*)d_in[9];
  const float* W_src= (const float*)d_in[10]; const float* W_dst= (const float*)d_in[11];
  const float* W_ea = (const float*)d_in[12]; const float* b_el = (const float*)d_in[13];
  const float* W_m  = (const float*)d_in[14]; const float* b_m  = (const float*)d_in[15];
  const float* W_n1 = (const float*)d_in[16]; const float* W_r1 = (const float*)d_in[17]; const float* b_c1 = (const float*)d_in[18];
  const float* W_n2 = (const float*)d_in[19]; const float* W_r2 = (const float*)d_in[20]; const float* b_c2 = (const float*)d_in[21];
  const float* W_l1 = (const float*)d_in[22]; const float* b_l1 = (const float*)d_in[23];
  const float* W_l2 = (const float*)d_in[24]; const float* b_l2 = (const float*)d_in[25];
  const int* eidx   = (const int*)d_in[26];
  const int* srcp   = eidx;
  const int* dstp   = eidx + kE;
  const int* community = (const int*)d_in[27];
  float* out = (float*)d_out;

  char* ws = (char*)d_ws;
  size_t off = 0;
  auto take = [&](size_t bytes)->char*{
    char* p = ws + off;
    off += (bytes + 511) & ~(size_t)511;
    return p;
  };
  const size_t NB2 = (size_t)kN*128*2;   // bf16 node buffer
  const size_t NB4 = (size_t)kN*128*4;   // fp32 node buffer
  short* hbuf  = (short*)take(NB2);
  short* h1buf = (short*)take(NB2);
  short* Abf16 = (short*)take(NB2);
  short* Bbf16 = (short*)take(NB2);
  float* p1f   = (float*)take(NB4);
  float* p2f   = (float*)take(NB4);
  char* z0 = ws + off;
  int* deg     = (int*)take((size_t)kN*4);
  int* cursor  = (int*)take((size_t)kN*4);
  int* ccnt    = (int*)take((size_t)kC*4);
  int* ccursor = (int*)take((size_t)kC*4);
  size_t zbytes = (size_t)((ws + off) - z0);
  int* offs    = (int*)take((size_t)(kN+1)*4);
  int* coffs   = (int*)take((size_t)(kC+1)*4);
  int* node_by_comm = (int*)take((size_t)kN*4);
  unsigned char* mask8 = (unsigned char*)take((size_t)kE*128);
  int* src_sorted  = (int*)take((size_t)kE*4);   // holds eids until k_fill, then src
  int* pos_of_edge = (int*)take((size_t)kE*4);
  size_t need = off;

  const int ntE   = (kE + 63) / 64;
  const int ntN64 = (kN + 63) / 64;

  if (ws_size >= need){
    hipMemsetAsync(z0, 0, zbytes, stream);
    k_hist    <<<(kE+255)/256, 256, 0, stream>>>(dstp, deg, community, ccnt);
    k_embed_ab<<<512, 512, 0, stream>>>(x, W_e1,b_e1, W_e2,b_e2, W_e3,b_e3,
                                        W_src, W_dst, b_el, hbuf, Abf16, Bbf16, ntN64);
    k_scan    <<<1, 1024, 0, stream>>>(deg, offs);
    k_scan_c  <<<1, 512, 0, stream>>>(ccnt, coffs);
    k_place   <<<(kE+255)/256, 256, 0, stream>>>(dstp, offs, cursor, src_sorted, kE);
    k_place   <<<(kN+255)/256, 256, 0, stream>>>(community, coffs, ccursor, node_by_comm, kN);
    k_sortseg <<<(kN+7)/8, 512, 0, stream>>>(offs, kN, src_sorted);
    k_sortseg <<<(kC+7)/8, 512, 0, stream>>>(coffs, kC, node_by_comm);
    k_fill    <<<(kE+255)/256, 256, 0, stream>>>(srcp, src_sorted, pos_of_edge);
    k_edge    <<<512, 512, 0, stream>>>(Abf16, Bbf16, ea, srcp, dstp, pos_of_edge,
                                        W_ee, b_ee, W_ea, W_m, b_m, mask8, ntE);
    k_conv    <<<ntN64, 512, 0, stream>>>(hbuf, mask8, src_sorted, offs,
                                          W_n1, W_r1, b_c1, h1buf, p1f, ntN64);
    k_conv    <<<ntN64, 512, 0, stream>>>(h1buf, mask8, src_sorted, offs,
                                          W_n2, W_r2, b_c2, nullptr, p2f, ntN64);
    k_final   <<<kC, 128, 0, stream>>>(p1f, p2f, node_by_comm, coffs,
                                       W_l1, b_l1, W_l2, b_l2, out);
  } else {
    k_diag<<<8, 256, 0, stream>>>(out, (float)(ws_size >> 20));
  }
}

// Round 17
// 488.369 us; speedup vs baseline: 1.1811x; 1.0854x over previous
//
#include <hip/hip_runtime.h>
#include <hip/hip_bf16.h>
#include <cstdint>
#include <cstddef>

#define kN 50000
#define kE 800000
#define kC 2000

using s8v = __attribute__((ext_vector_type(8))) short;   // 8 bf16 (4 VGPRs) — MFMA A/B frag
using s4v = __attribute__((ext_vector_type(4))) short;
using f4v = __attribute__((ext_vector_type(4))) float;   // MFMA C/D frag

// cast-based bf16 convert -> compiler emits native v_cvt_pk_bf16_f32 pairs (T12/m240)
__device__ __forceinline__ short f2bf(float x){
  __hip_bfloat16 h = __float2bfloat16(x);
  return *reinterpret_cast<short*>(&h);
}
__device__ __forceinline__ float bf2f(short s){
  union { unsigned u; float f; } v; v.u = ((unsigned)(unsigned short)s) << 16;
  return v.f;
}

// ---------------- histogram: deg[dst], community counts ----------------
__global__ __launch_bounds__(256) void k_hist(const int* __restrict__ dst, int* __restrict__ deg,
                                              const int* __restrict__ community, int* __restrict__ ccnt){
  int i = blockIdx.x*256 + threadIdx.x;
  if (i < kE) atomicAdd(&deg[dst[i]], 1);
  if (i < kN) atomicAdd(&ccnt[community[i]], 1);
}

// ---------------- exclusive scan of deg -> offsets [kN+1], 4 elems/thread ----------------
__global__ __launch_bounds__(1024) void k_scan(const int* __restrict__ deg, int* __restrict__ offs){
  __shared__ int s_wsum[16];
  __shared__ int s_woff[17];
  __shared__ int s_carry;
  int t = threadIdx.x, lane = t & 63, w = t >> 6;
  if (t == 0) s_carry = 0;
  __syncthreads();
  for (int base = 0; base < kN; base += 4096){
    int i = base + t*4;
    int4 v = {0,0,0,0};
    if (i < kN) v = *reinterpret_cast<const int4*>(&deg[i]);   // kN % 4 == 0
    int s = v.x + v.y + v.z + v.w;
    int x = s;
    #pragma unroll
    for (int off = 1; off < 64; off <<= 1){
      int y = __shfl_up(x, off);
      if (lane >= off) x += y;
    }
    if (lane == 63) s_wsum[w] = x;
    __syncthreads();
    if (t == 0){
      int acc = 0;
      for (int q = 0; q < 16; q++){ s_woff[q] = acc; acc += s_wsum[q]; }
      s_woff[16] = acc;
    }
    __syncthreads();
    if (i < kN){
      int pre = s_carry + s_woff[w] + (x - s);
      int4 o; o.x = pre; o.y = pre + v.x; o.z = pre + v.x + v.y; o.w = pre + v.x + v.y + v.z;
      *reinterpret_cast<int4*>(&offs[i]) = o;
    }
    __syncthreads();
    if (t == 0) s_carry += s_woff[16];
    __syncthreads();
  }
  if (t == 0) offs[kN] = s_carry;   // == kE
}

// ---------------- exclusive scan of ccnt (kC=2000) -> coffs [kC+1], one pass ----------------
__global__ __launch_bounds__(512) void k_scan_c(const int* __restrict__ ccnt, int* __restrict__ coffs){
  __shared__ int s_wsum[8];
  __shared__ int s_woff[9];
  int t = threadIdx.x, lane = t & 63, w = t >> 6;
  int i = t*4;
  int4 v = {0,0,0,0};
  if (i < kC) v = *reinterpret_cast<const int4*>(&ccnt[i]);   // kC % 4 == 0
  int s = v.x + v.y + v.z + v.w;
  int x = s;
  #pragma unroll
  for (int off = 1; off < 64; off <<= 1){
    int y = __shfl_up(x, off);
    if (lane >= off) x += y;
  }
  if (lane == 63) s_wsum[w] = x;
  __syncthreads();
  if (t == 0){
    int a = 0;
    for (int q = 0; q < 8; q++){ s_woff[q] = a; a += s_wsum[q]; }
    s_woff[8] = a;
  }
  __syncthreads();
  if (i < kC){
    int pre = s_woff[w] + (x - s);
    int4 o; o.x = pre; o.y = pre + v.x; o.z = pre + v.x + v.y; o.w = pre + v.x + v.y + v.z;
    *reinterpret_cast<int4*>(&coffs[i]) = o;
  }
  if (t == 0) coffs[kC] = s_woff[8];   // == kN
}

// ---------------- place ids at atomic positions (order fixed later by k_sortseg) ----------------
__global__ __launch_bounds__(256) void k_place(const int* __restrict__ key, const int* __restrict__ offs,
                                               int* __restrict__ cursor, int* __restrict__ id_out, int nitems){
  int e = blockIdx.x*256 + threadIdx.x;
  if (e >= nitems) return;
  int d = key[e];
  int p = offs[d] + atomicAdd(&cursor[d], 1);
  id_out[p] = e;
}

// ---------------- deterministic segment sort: one wave per segment, ids ascending ----------------
__global__ __launch_bounds__(512) void k_sortseg(const int* __restrict__ offs, int nseg, int* __restrict__ ids){
  __shared__ int buf[8][256];
  int w = threadIdx.x >> 6, lane = threadIdx.x & 63;
  int seg = blockIdx.x*8 + w;
  if (seg >= nseg) return;
  int s0 = offs[seg], s1 = offs[seg+1];
  int len = s1 - s0;
  if (len <= 1 || len > 256) return;
  int* b = buf[w];
  for (int i = lane; i < len; i += 64) b[i] = ids[s0 + i];
  for (int i = lane; i < len; i += 64){
    int my = b[i];
    int r = 0;
    for (int j = 0; j < len; j++) r += (b[j] < my);
    ids[s0 + r] = my;
  }
}

// ---------------- build pos_of_edge + src_sorted from sorted eids (in place) ----------------
__global__ __launch_bounds__(256) void k_fill(const int* __restrict__ src,
                                              int* __restrict__ eid_then_src,
                                              int* __restrict__ pos_of_edge){
  int p = blockIdx.x*256 + threadIdx.x;
  if (p >= kE) return;
  int eid = eid_then_src[p];
  pos_of_edge[eid] = p;
  eid_then_src[p] = src[eid];
}

// ---------------- fused embed + A/B: x -> xe (VALU) -> h (MFMA) -> A,B (MFMA) ----------------
__global__ __launch_bounds__(512, 2) void k_embed_ab(
    const float* __restrict__ x,
    const float* __restrict__ W_e1, const float* __restrict__ b_e1,
    const float* __restrict__ W_e2, const float* __restrict__ b_e2,
    const float* __restrict__ W_e3, const float* __restrict__ b_e3,
    const float* __restrict__ W_src, const float* __restrict__ W_dst, const float* __restrict__ b_el,
    short* __restrict__ Hout, short* __restrict__ Aout, short* __restrict__ Bout, int ntiles)
{
  __shared__ short s_W[2][128][136];   // staging, reused as s_xe/s_h
  __shared__ float s_x[64][28];
  __shared__ float s_b3[128], s_bel[128];
  int tid = threadIdx.x;
  int lane = tid & 63, w = tid >> 6, lo = lane & 15, hi = lane >> 4;
  for (int idx = tid; idx < 128*128; idx += 512){
    int f = idx & 127, k = idx >> 7;
    s_W[0][f][k] = f2bf(W_e3[k*128 + f]);
    s_W[1][f][k] = f2bf(W_src[k*128 + f]);
  }
  if (tid < 128){ s_b3[tid] = b_e3[tid]; s_bel[tid] = b_el[tid]; }
  __syncthreads();
  s8v fe3[4], fsrc[4], fdst[4];
  #pragma unroll
  for (int ks = 0; ks < 4; ks++){
    fe3[ks]  = *(const s8v*)&s_W[0][w*16 + lo][ks*32 + hi*8];
    fsrc[ks] = *(const s8v*)&s_W[1][w*16 + lo][ks*32 + hi*8];
  }
  __syncthreads();
  for (int idx = tid; idx < 128*128; idx += 512){
    int f = idx & 127, k = idx >> 7;
    s_W[0][f][k] = f2bf(W_dst[k*128 + f]);
  }
  __syncthreads();
  #pragma unroll
  for (int ks = 0; ks < 4; ks++) fdst[ks] = *(const s8v*)&s_W[0][w*16 + lo][ks*32 + hi*8];

  short (*s_xe)[136] = s_W[0];
  short (*s_h)[136]  = s_W[1];

  for (int tile = blockIdx.x; tile < ntiles; tile += gridDim.x){
    int n0 = tile << 6;
    __syncthreads();
    for (int idx = tid; idx < 64*26; idx += 512){
      int nl = idx / 26, i = idx - nl*26; int n = n0 + nl;
      s_x[nl][i] = (n < kN) ? x[(size_t)n*26 + i] : 0.f;
    }
    __syncthreads();
    #pragma unroll
    for (int r = 0; r < 16; r++){
      int idx = (r << 9) + tid; int nl = idx >> 7, j = idx & 127;
      float a;
      if (j < 64){
        a = b_e1[j];
        #pragma unroll
        for (int i = 0; i < 14; i++) a += s_x[nl][i] * W_e1[i*64 + j];
      } else {
        int jj = j - 64;
        a = b_e2[jj];
        #pragma unroll
        for (int i = 0; i < 12; i++) a += s_x[nl][14 + i] * W_e2[i*64 + jj];
      }
      s_xe[nl][j] = f2bf(fmaxf(a, 0.f));
    }
    __syncthreads();
    #pragma unroll
    for (int et = 0; et < 4; et++){
      f4v acc = {0.f,0.f,0.f,0.f};
      #pragma unroll
      for (int ks = 0; ks < 4; ks++){
        s8v b = *(const s8v*)&s_xe[et*16 + lo][ks*32 + hi*8];
        acc = __builtin_amdgcn_mfma_f32_16x16x32_bf16(fe3[ks], b, acc, 0, 0, 0);
      }
      int n = n0 + et*16 + lo, f0 = w*16 + hi*4;
      s4v hv;
      #pragma unroll
      for (int j = 0; j < 4; j++) hv[j] = f2bf(fmaxf(acc[j] + s_b3[f0 + j], 0.f));
      *(s4v*)&s_h[et*16 + lo][f0] = hv;
      if (n < kN) *(s4v*)&Hout[(size_t)n*128 + f0] = hv;
    }
    __syncthreads();
    #pragma unroll
    for (int et = 0; et < 4; et++){
      f4v aA = {0.f,0.f,0.f,0.f}, aB = {0.f,0.f,0.f,0.f};
      #pragma unroll
      for (int ks = 0; ks < 4; ks++){
        s8v b = *(const s8v*)&s_h[et*16 + lo][ks*32 + hi*8];
        aA = __builtin_amdgcn_mfma_f32_16x16x32_bf16(fsrc[ks], b, aA, 0, 0, 0);
        aB = __builtin_amdgcn_mfma_f32_16x16x32_bf16(fdst[ks], b, aB, 0, 0, 0);
      }
      int n = n0 + et*16 + lo, f0 = w*16 + hi*4;
      if (n < kN){
        s4v Av, Bv;
        #pragma unroll
        for (int j = 0; j < 4; j++){ Av[j] = f2bf(aA[j] + s_bel[f0 + j]); Bv[j] = f2bf(aB[j]); }
        *(s4v*)&Aout[(size_t)n*128 + f0] = Av;
        *(s4v*)&Bout[(size_t)n*128 + f0] = Bv;
      }
    }
  }
}

// ---------------- per-edge kernel: MFMA bf16, 64 edges/tile, 8 waves (round-14 proven, UNCHANGED) ----------------
#define RO_EEMB 0        // short[64][72]  = 9216
#define RO_HE   9216     // short[64][136] = 17408 (end 26624)
#define RO_BIAS 26624    // short[64][136] = 17408 (end 44032)
#define RO_WEE  44032    // float[512]     = 2048
#define RO_BEE  46080    // float[64]      = 256
#define RO_BM   46336    // float[128]     = 512 (end 46848)
#define KE_LDS  46848
__global__ __launch_bounds__(512, 4) void k_edge(
    const short* __restrict__ Abf, const short* __restrict__ Bbf,
    const float* __restrict__ edge_attr,
    const int* __restrict__ src, const int* __restrict__ dst,
    const int* __restrict__ posp,
    const float* __restrict__ W_ee, const float* __restrict__ b_ee,
    const float* __restrict__ W_ea, const float* __restrict__ W_m,
    const float* __restrict__ b_m,
    unsigned char* __restrict__ mask_out,
    int ntiles)
{
  __shared__ __align__(16) char smem[KE_LDS];
  short (*s_eemb)[72]  = (short(*)[72])(smem + RO_EEMB);
  short (*s_he)[136]   = (short(*)[136])(smem + RO_HE);
  short (*s_bias)[136] = (short(*)[136])(smem + RO_BIAS);
  float *s_Wee = (float*)(smem + RO_WEE);
  float *s_bee = (float*)(smem + RO_BEE);
  float *s_bm  = (float*)(smem + RO_BM);

  int tid = threadIdx.x;
  const int lane = tid & 63, w = tid >> 6;
  const int lo = lane & 15, hi = lane >> 4;

  s8v a1[2], a2[4];
  {
    short (*s_stg)[72] = (short(*)[72])smem;
    for (int idx = tid; idx < 128*64; idx += 512){ int f = idx & 127, k = idx >> 7; s_stg[f][k] = f2bf(W_ea[k*128+f]); }
    __syncthreads();
    #pragma unroll
    for (int ks = 0; ks < 2; ks++) a1[ks] = *(const s8v*)&s_stg[16*w + lo][ks*32 + hi*8];
    __syncthreads();
  }
  {
    short (*s_stg)[136] = (short(*)[136])smem;
    for (int idx = tid; idx < 128*128; idx += 512){ int f = idx & 127, k = idx >> 7; s_stg[f][k] = f2bf(W_m[k*128+f]); }
    __syncthreads();
    #pragma unroll
    for (int ks = 0; ks < 4; ks++) a2[ks] = *(const s8v*)&s_stg[16*w + lo][ks*32 + hi*8];
    __syncthreads();
  }
  s_Wee[tid] = W_ee[tid];
  if (tid < 64) s_bee[tid] = b_ee[tid];
  if (tid >= 64 && tid < 192) s_bm[tid-64] = b_m[tid-64];
  __syncthreads();

  const int el8 = tid >> 3, kb = (tid & 7) << 3;
  const int p16 = (tid & 7) << 4;
  const int f0 = 16*w + hi*4;

  for (int tile = blockIdx.x; tile < ntiles; tile += gridDim.x){
    int e0 = tile << 6;
    // phase b: direct per-thread loads (edge el8), A/B gathers + eemb + bias
    {
      int eg = e0 + el8;
      int sr = src[eg], dr = dst[eg];
      float4 ea0 = *reinterpret_cast<const float4*>(&edge_attr[(size_t)eg*8]);
      float4 ea1 = *reinterpret_cast<const float4*>(&edge_attr[(size_t)eg*8 + 4]);
      int sb = sr*128 + p16, db = dr*128 + p16;
      s8v av0 = *(const s8v*)(Abf + sb);
      s8v av1 = *(const s8v*)(Abf + sb + 8);
      s8v bv0 = *(const s8v*)(Bbf + db);
      s8v bv1 = *(const s8v*)(Bbf + db + 8);
      float eav[8] = {ea0.x, ea0.y, ea0.z, ea0.w, ea1.x, ea1.y, ea1.z, ea1.w};
      float ee_[8];
      #pragma unroll
      for (int j = 0; j < 8; j++){
        float acc = s_bee[kb + j];
        #pragma unroll
        for (int i = 0; i < 8; i++) acc += eav[i] * s_Wee[i*64 + kb + j];
        ee_[j] = fmaxf(acc, 0.f);
      }
      s8v ep;
      #pragma unroll
      for (int j = 0; j < 8; j++) ep[j] = f2bf(ee_[j]);
      *(s8v*)&s_eemb[el8][kb] = ep;
      s8v b0, b1;
      #pragma unroll
      for (int q = 0; q < 8; q++){
        b0[q] = f2bf(bf2f(av0[q]) + bf2f(bv0[q]));
        b1[q] = f2bf(bf2f(av1[q]) + bf2f(bv1[q]));
      }
      *(s8v*)&s_bias[el8][p16]     = b0;
      *(s8v*)&s_bias[el8][p16 + 8] = b1;
    }
    __syncthreads();
    // phase c: GEMM1 (K=64), acc init = bias
    #pragma unroll
    for (int et = 0; et < 4; et++){
      int e = et*16 + lo;
      s4v bb = *(const s4v*)&s_bias[e][f0];
      f4v acc;
      #pragma unroll
      for (int j = 0; j < 4; j++) acc[j] = bf2f(bb[j]);
      #pragma unroll
      for (int ks = 0; ks < 2; ks++){
        s8v bfrag = *(const s8v*)&s_eemb[e][ks*32 + hi*8];
        acc = __builtin_amdgcn_mfma_f32_16x16x32_bf16(a1[ks], bfrag, acc, 0, 0, 0);
      }
      s4v hw;
      #pragma unroll
      for (int j = 0; j < 4; j++) hw[j] = f2bf(fmaxf(acc[j], 0.f));
      *(s4v*)&s_he[e][f0] = hw;
    }
    __syncthreads();
    // phase d: GEMM2 (K=128) -> fast-sigmoid -> packed u8 store
    #pragma unroll
    for (int et = 0; et < 4; et++){
      int e = et*16 + lo;
      int pe = posp[e0 + e];
      f4v acc = {0.f, 0.f, 0.f, 0.f};
      #pragma unroll
      for (int ks = 0; ks < 4; ks++){
        s8v bfrag = *(const s8v*)&s_he[e][ks*32 + hi*8];
        acc = __builtin_amdgcn_mfma_f32_16x16x32_bf16(a2[ks], bfrag, acc, 0, 0, 0);
      }
      unsigned pk = 0;
      #pragma unroll
      for (int j = 0; j < 4; j++){
        float ex = __expf(-(acc[j] + s_bm[f0 + j]));
        float m255 = __fdividef(255.f, 1.f + ex);
        pk |= (__float2uint_rn(m255) & 255u) << (j*8);
      }
      *reinterpret_cast<unsigned*>(&mask_out[(size_t)pe*128 + f0]) = pk;
    }
    __syncthreads();
  }
}

// ---------------- fused conv layer: gather-aggregate + (agg@Wn + h@Wr) MFMA ----------------
// Round 17: (512,6) -> (512,4). The unified-file split model (rounds 9-11) says
// (512,6) caps arch VGPRs at ~40; k_conv's live set (acc[16] fp32 + 20 prefetch regs
// + CSR state) exceeds that -> it has likely been spilling silently since round 11
// (never surfaced in top-5 counters). (512,4) = arch cap 64, the proven no-spill
// point. Also: clamp-index prefetch (branch-free issue).
__global__ __launch_bounds__(512, 4) void k_conv(
    const short* __restrict__ Hbf,
    const unsigned char* __restrict__ mask8,
    const int* __restrict__ src_sorted, const int* __restrict__ offs,
    const float* __restrict__ Wn, const float* __restrict__ Wr, const float* __restrict__ bc,
    short* __restrict__ Hout, float* __restrict__ Pout, int ntiles)
{
  __shared__ short s_buf[128][136];
  __shared__ float s_bc[128];
  int tid = threadIdx.x;
  int lane = tid & 63, w = tid >> 6, lo = lane & 15, hi = lane >> 4;
  s8v fn[4], fr[4];
  for (int idx = tid; idx < 128*128; idx += 512){
    int f = idx & 127, k = idx >> 7;
    s_buf[f][k] = f2bf(Wn[k*128 + f]);
  }
  if (tid < 128) s_bc[tid] = bc[tid];
  __syncthreads();
  #pragma unroll
  for (int ks = 0; ks < 4; ks++) fn[ks] = *(const s8v*)&s_buf[w*16 + lo][ks*32 + hi*8];
  __syncthreads();
  for (int idx = tid; idx < 128*128; idx += 512){
    int f = idx & 127, k = idx >> 7;
    s_buf[f][k] = f2bf(Wr[k*128 + f]);
  }
  __syncthreads();
  #pragma unroll
  for (int ks = 0; ks < 4; ks++) fr[ks] = *(const s8v*)&s_buf[w*16 + lo][ks*32 + hi*8];

  short (*s_agg)[136] = s_buf;        // rows 0..63
  short (*s_h)[136]   = s_buf + 64;   // rows 64..127
  const int nl8 = tid >> 3, p16 = (tid & 7) << 4;

  for (int tile = blockIdx.x; tile < ntiles; tile += gridDim.x){
    int n0 = tile << 6;
    __syncthreads();
    int n = n0 + nl8;
    {
      s8v h0 = {0,0,0,0,0,0,0,0}, h1 = {0,0,0,0,0,0,0,0};
      if (n < kN){
        h0 = *(const s8v*)&Hbf[(size_t)n*128 + p16];
        h1 = *(const s8v*)&Hbf[(size_t)n*128 + p16 + 8];
      }
      *(s8v*)&s_h[nl8][p16] = h0;
      *(s8v*)&s_h[nl8][p16 + 8] = h1;
    }
    float acc[16];
    #pragma unroll
    for (int q = 0; q < 16; q++) acc[q] = 0.f;
    int s0 = 0, s1 = 0;
    if (n < kN){ s0 = offs[n]; s1 = offs[n+1]; }
    int4 mv_c = {0,0,0,0}; s8v g0_c = {0,0,0,0,0,0,0,0}, g1_c = {0,0,0,0,0,0,0,0};
    if (s0 < s1){
      int sv = src_sorted[s0];
      mv_c = *reinterpret_cast<const int4*>(&mask8[(size_t)s0*128 + p16]);
      g0_c = *(const s8v*)&Hbf[(size_t)sv*128 + p16];
      g1_c = *(const s8v*)&Hbf[(size_t)sv*128 + p16 + 8];
    }
    for (int i = s0; i < s1; i++){
      int4 mv = mv_c; s8v g0 = g0_c, g1 = g1_c;
      // clamp-index prefetch: branch-free, last iter reloads current (harmless)
      int nx = (i + 1 < s1) ? i + 1 : i;
      int svn = src_sorted[nx];
      mv_c = *reinterpret_cast<const int4*>(&mask8[(size_t)nx*128 + p16]);
      g0_c = *(const s8v*)&Hbf[(size_t)svn*128 + p16];
      g1_c = *(const s8v*)&Hbf[(size_t)svn*128 + p16 + 8];
      unsigned mw[4] = {(unsigned)mv.x, (unsigned)mv.y, (unsigned)mv.z, (unsigned)mv.w};
      float mf16[16];
      #pragma unroll
      for (int d = 0; d < 4; d++){
        mf16[d*4+0] = (float)( mw[d]        & 255u);
        mf16[d*4+1] = (float)((mw[d] >>  8) & 255u);
        mf16[d*4+2] = (float)((mw[d] >> 16) & 255u);
        mf16[d*4+3] = (float)( mw[d] >> 24       );
      }
      #pragma unroll
      for (int q = 0; q < 8; q++) acc[q]     += bf2f(g0[q]) * mf16[q];
      #pragma unroll
      for (int q = 0; q < 8; q++) acc[8 + q] += bf2f(g1[q]) * mf16[8 + q];
    }
    float inv = (1.f/255.f) * __fdividef(1.f, fmaxf((float)(s1 - s0), 1.f));
    {
      s8v a0, a1;
      #pragma unroll
      for (int q = 0; q < 8; q++){ a0[q] = f2bf(acc[q]*inv); a1[q] = f2bf(acc[8+q]*inv); }
      *(s8v*)&s_agg[nl8][p16] = a0;
      *(s8v*)&s_agg[nl8][p16 + 8] = a1;
    }
    __syncthreads();
    #pragma unroll
    for (int et = 0; et < 4; et++){
      f4v ac = {0.f,0.f,0.f,0.f};
      #pragma unroll
      for (int ks = 0; ks < 4; ks++){
        s8v bA = *(const s8v*)&s_agg[et*16 + lo][ks*32 + hi*8];
        ac = __builtin_amdgcn_mfma_f32_16x16x32_bf16(fn[ks], bA, ac, 0, 0, 0);
        s8v bH = *(const s8v*)&s_h[et*16 + lo][ks*32 + hi*8];
        ac = __builtin_amdgcn_mfma_f32_16x16x32_bf16(fr[ks], bH, ac, 0, 0, 0);
      }
      int nn = n0 + et*16 + lo, f0 = w*16 + hi*4;
      if (nn < kN){
        s4v hv; float4 pv;
        float v0 = fmaxf(ac[0] + s_bc[f0 + 0], 0.f);
        float v1 = fmaxf(ac[1] + s_bc[f0 + 1], 0.f);
        float v2 = fmaxf(ac[2] + s_bc[f0 + 2], 0.f);
        float v3 = fmaxf(ac[3] + s_bc[f0 + 3], 0.f);
        hv[0] = f2bf(v0); hv[1] = f2bf(v1); hv[2] = f2bf(v2); hv[3] = f2bf(v3);
        pv.x = v0; pv.y = v1; pv.z = v2; pv.w = v3;
        if (Hout) *(s4v*)&Hout[(size_t)nn*128 + f0] = hv;
        *reinterpret_cast<float4*>(&Pout[(size_t)nn*128 + f0]) = pv;
      }
    }
  }
}

// ---------------- final: community gather-pool (mean+max, no atomics) + MLP ----------------
__global__ __launch_bounds__(128) void k_final(
    const float* __restrict__ p1f, const float* __restrict__ p2f,
    const int* __restrict__ node_by_comm, const int* __restrict__ coffs,
    const float* __restrict__ W_l1, const float* __restrict__ b_l1,
    const float* __restrict__ W_l2, const float* __restrict__ b_l2,
    float* __restrict__ out)
{
  __shared__ float p[256];
  __shared__ float red[2];
  int c = blockIdx.x, t = threadIdx.x;
  int c0 = coffs[c], c1 = coffs[c+1];
  float s = 0.f, m1 = 0.f, m2 = 0.f;
  float v1_c = 0.f, v2_c = 0.f;
  if (c0 < c1){
    int n = node_by_comm[c0];
    v1_c = p1f[(size_t)n*128 + t];
    v2_c = p2f[(size_t)n*128 + t];
  }
  for (int i = c0; i < c1; i++){
    float v1 = v1_c, v2 = v2_c;
    if (i + 1 < c1){
      int nn = node_by_comm[i + 1];
      v1_c = p1f[(size_t)nn*128 + t];
      v2_c = p2f[(size_t)nn*128 + t];
    }
    s += v1 + v2;
    m1 = fmaxf(m1, v1);
    m2 = fmaxf(m2, v2);
  }
  float inv = 1.f / fmaxf((float)(c1 - c0), 1.f);
  p[t]       = s * inv;
  p[128 + t] = m1 + m2;
  __syncthreads();
  float acc = b_l1[t];
  for (int g = 0; g < 256; g++) acc += p[g]*W_l1[g*128+t];
  float hv = fmaxf(acc, 0.f) * W_l2[t];
  #pragma unroll
  for (int off = 32; off > 0; off >>= 1) hv += __shfl_down(hv, off);
  if ((t & 63) == 0) red[t>>6] = hv;
  __syncthreads();
  if (t == 0) out[c] = red[0] + red[1] + b_l2[0];
}

// diagnostic: surface ws_size through the absmax if workspace is too small
__global__ void k_diag(float* out, float v){
  int i = blockIdx.x*256 + threadIdx.x;
  if (i < kC) out[i] = v;
}

extern "C" void kernel_launch(void* const* d_in, const int* in_sizes, int n_in,
                              void* d_out, int out_size, void* d_ws, size_t ws_size,
                              hipStream_t stream)
{
  const float* x    = (const float*)d_in[0];
  const float* ea   = (const float*)d_in[1];
  const float* W_ee = (const float*)d_in[2];  const float* b_ee = (const float*)d_in[3];
  const float* W_e1 = (const float*)d_in[4];  const float* b_e1 = (const float*)d_in[5];
  const float* W_e2 = (const float*)d_in[6];  const float* b_e2 = (const float*)d_in[7];
  const float* W_e3 = (const float*)d_in[8];  const float* b_e3 = (const float*)d_in[9];
  const float* W_src= (const float*)d_in[10]; const float* W_dst= (const float*)d_in[11];
  const float* W_ea = (const float*)d_in[12]; const float* b_el = (const float*)d_in[13];
  const float* W_m  = (const float*)d_in[14]; const float* b_m  = (const float*)d_in[15];
  const float* W_n1 = (const float*)d_in[16]; const float* W_r1 = (const float*)d_in[17]; const float* b_c1 = (const float*)d_in[18];
  const float* W_n2 = (const float*)d_in[19]; const float* W_r2 = (const float*)d_in[20]; const float* b_c2 = (const float*)d_in[21];
  const float* W_l1 = (const float*)d_in[22]; const float* b_l1 = (const float*)d_in[23];
  const float* W_l2 = (const float*)d_in[24]; const float* b_l2 = (const float*)d_in[25];
  const int* eidx   = (const int*)d_in[26];
  const int* srcp   = eidx;
  const int* dstp   = eidx + kE;
  const int* community = (const int*)d_in[27];
  float* out = (float*)d_out;

  char* ws = (char*)d_ws;
  size_t off = 0;
  auto take = [&](size_t bytes)->char*{
    char* p = ws + off;
    off += (bytes + 511) & ~(size_t)511;
    return p;
  };
  const size_t NB2 = (size_t)kN*128*2;   // bf16 node buffer
  const size_t NB4 = (size_t)kN*128*4;   // fp32 node buffer
  short* hbuf  = (short*)take(NB2);
  short* h1buf = (short*)take(NB2);
  short* Abf16 = (short*)take(NB2);
  short* Bbf16 = (short*)take(NB2);
  float* p1f   = (float*)take(NB4);
  float* p2f   = (float*)take(NB4);
  char* z0 = ws + off;
  int* deg     = (int*)take((size_t)kN*4);
  int* cursor  = (int*)take((size_t)kN*4);
  int* ccnt    = (int*)take((size_t)kC*4);
  int* ccursor = (int*)take((size_t)kC*4);
  size_t zbytes = (size_t)((ws + off) - z0);
  int* offs    = (int*)take((size_t)(kN+1)*4);
  int* coffs   = (int*)take((size_t)(kC+1)*4);
  int* node_by_comm = (int*)take((size_t)kN*4);
  unsigned char* mask8 = (unsigned char*)take((size_t)kE*128);
  int* src_sorted  = (int*)take((size_t)kE*4);   // holds eids until k_fill, then src
  int* pos_of_edge = (int*)take((size_t)kE*4);
  size_t need = off;

  const int ntE   = (kE + 63) / 64;
  const int ntN64 = (kN + 63) / 64;

  if (ws_size >= need){
    hipMemsetAsync(z0, 0, zbytes, stream);
    k_hist    <<<(kE+255)/256, 256, 0, stream>>>(dstp, deg, community, ccnt);
    k_embed_ab<<<512, 512, 0, stream>>>(x, W_e1,b_e1, W_e2,b_e2, W_e3,b_e3,
                                        W_src, W_dst, b_el, hbuf, Abf16, Bbf16, ntN64);
    k_scan    <<<1, 1024, 0, stream>>>(deg, offs);
    k_scan_c  <<<1, 512, 0, stream>>>(ccnt, coffs);
    k_place   <<<(kE+255)/256, 256, 0, stream>>>(dstp, offs, cursor, src_sorted, kE);
    k_place   <<<(kN+255)/256, 256, 0, stream>>>(community, coffs, ccursor, node_by_comm, kN);
    k_sortseg <<<(kN+7)/8, 512, 0, stream>>>(offs, kN, src_sorted);
    k_sortseg <<<(kC+7)/8, 512, 0, stream>>>(coffs, kC, node_by_comm);
    k_fill    <<<(kE+255)/256, 256, 0, stream>>>(srcp, src_sorted, pos_of_edge);
    k_edge    <<<512, 512, 0, stream>>>(Abf16, Bbf16, ea, srcp, dstp, pos_of_edge,
                                        W_ee, b_ee, W_ea, W_m, b_m, mask8, ntE);
    k_conv    <<<ntN64, 512, 0, stream>>>(hbuf, mask8, src_sorted, offs,
                                          W_n1, W_r1, b_c1, h1buf, p1f, ntN64);
    k_conv    <<<ntN64, 512, 0, stream>>>(h1buf, mask8, src_sorted, offs,
                                          W_n2, W_r2, b_c2, nullptr, p2f, ntN64);
    k_final   <<<kC, 128, 0, stream>>>(p1f, p2f, node_by_comm, coffs,
                                       W_l1, b_l1, W_l2, b_l2, out);
  } else {
    k_diag<<<8, 256, 0, stream>>>(out, (float)(ws_size >> 20));
  }
}

// Round 18
// 472.367 us; speedup vs baseline: 1.2211x; 1.0339x over previous
//
#include <hip/hip_runtime.h>
#include <hip/hip_bf16.h>
#include <cstdint>
#include <cstddef>

#define kN 50000
#define kE 800000
#define kC 2000

using s8v = __attribute__((ext_vector_type(8))) short;   // 8 bf16 (4 VGPRs) — MFMA A/B frag
using s4v = __attribute__((ext_vector_type(4))) short;
using f4v = __attribute__((ext_vector_type(4))) float;   // MFMA C/D frag

// cast-based bf16 convert -> compiler emits native v_cvt_pk_bf16_f32 pairs (T12/m240)
__device__ __forceinline__ short f2bf(float x){
  __hip_bfloat16 h = __float2bfloat16(x);
  return *reinterpret_cast<short*>(&h);
}
__device__ __forceinline__ float bf2f(short s){
  union { unsigned u; float f; } v; v.u = ((unsigned)(unsigned short)s) << 16;
  return v.f;
}

// ---------------- histogram: deg[dst], community counts ----------------
__global__ __launch_bounds__(256) void k_hist(const int* __restrict__ dst, int* __restrict__ deg,
                                              const int* __restrict__ community, int* __restrict__ ccnt){
  int i = blockIdx.x*256 + threadIdx.x;
  if (i < kE) atomicAdd(&deg[dst[i]], 1);
  if (i < kN) atomicAdd(&ccnt[community[i]], 1);
}

// ---------------- two-level parallel scan of deg (round 18: was 1-block serial) ----------------
// phase 1: per-block (4096 elems) exclusive scan + block sum
__global__ __launch_bounds__(1024) void k_scan1(const int* __restrict__ deg, int* __restrict__ offs,
                                                int* __restrict__ bsum){
  __shared__ int s_wsum[16];
  __shared__ int s_woff[17];
  int t = threadIdx.x, lane = t & 63, w = t >> 6;
  int i = blockIdx.x*4096 + t*4;
  int4 v = {0,0,0,0};
  if (i < kN) v = *reinterpret_cast<const int4*>(&deg[i]);   // kN % 4 == 0
  int s = v.x + v.y + v.z + v.w;
  int x = s;
  #pragma unroll
  for (int off = 1; off < 64; off <<= 1){
    int y = __shfl_up(x, off);
    if (lane >= off) x += y;
  }
  if (lane == 63) s_wsum[w] = x;
  __syncthreads();
  if (t == 0){
    int a = 0;
    for (int q = 0; q < 16; q++){ s_woff[q] = a; a += s_wsum[q]; }
    s_woff[16] = a;
  }
  __syncthreads();
  if (i < kN){
    int pre = s_woff[w] + (x - s);
    int4 o; o.x = pre; o.y = pre + v.x; o.z = pre + v.x + v.y; o.w = pre + v.x + v.y + v.z;
    *reinterpret_cast<int4*>(&offs[i]) = o;
  }
  if (t == 0) bsum[blockIdx.x] = s_woff[16];
}
// phase 2: add scanned block offsets (each block redundantly scans the 13 sums — cheap)
__global__ __launch_bounds__(1024) void k_scan2(int* __restrict__ offs, const int* __restrict__ bsum, int nblk){
  __shared__ int s_pre[32];
  if (threadIdx.x == 0){
    int a = 0;
    for (int q = 0; q < nblk; q++){ s_pre[q] = a; a += bsum[q]; }
    s_pre[nblk] = a;
  }
  __syncthreads();
  int i = blockIdx.x*1024 + threadIdx.x;
  if (i < kN) offs[i] += s_pre[i >> 12];     // 4096 = 1<<12
  if (i == 0) offs[kN] = s_pre[nblk];        // grand total == kE
}

// ---------------- exclusive scan of ccnt (kC=2000) -> coffs [kC+1], one pass ----------------
__global__ __launch_bounds__(512) void k_scan_c(const int* __restrict__ ccnt, int* __restrict__ coffs){
  __shared__ int s_wsum[8];
  __shared__ int s_woff[9];
  int t = threadIdx.x, lane = t & 63, w = t >> 6;
  int i = t*4;
  int4 v = {0,0,0,0};
  if (i < kC) v = *reinterpret_cast<const int4*>(&ccnt[i]);   // kC % 4 == 0
  int s = v.x + v.y + v.z + v.w;
  int x = s;
  #pragma unroll
  for (int off = 1; off < 64; off <<= 1){
    int y = __shfl_up(x, off);
    if (lane >= off) x += y;
  }
  if (lane == 63) s_wsum[w] = x;
  __syncthreads();
  if (t == 0){
    int a = 0;
    for (int q = 0; q < 8; q++){ s_woff[q] = a; a += s_wsum[q]; }
    s_woff[8] = a;
  }
  __syncthreads();
  if (i < kC){
    int pre = s_woff[w] + (x - s);
    int4 o; o.x = pre; o.y = pre + v.x; o.z = pre + v.x + v.y; o.w = pre + v.x + v.y + v.z;
    *reinterpret_cast<int4*>(&coffs[i]) = o;
  }
  if (t == 0) coffs[kC] = s_woff[8];   // == kN
}

// ---------------- place ids at atomic positions (order fixed later by k_sortseg) ----------------
__global__ __launch_bounds__(256) void k_place(const int* __restrict__ key, const int* __restrict__ offs,
                                               int* __restrict__ cursor, int* __restrict__ id_out, int nitems){
  int e = blockIdx.x*256 + threadIdx.x;
  if (e >= nitems) return;
  int d = key[e];
  int p = offs[d] + atomicAdd(&cursor[d], 1);
  id_out[p] = e;
}

// ---------------- deterministic segment sort + optional id->src conversion ----------------
// Rank-scatter per wave; when conv_src != null also fills pos_of[id] and rewrites
// ids[] with src[id] (folds the old k_fill pass in). len<=256 guaranteed
// (Poisson(16)/(25) segments; P(len>256) < 1e-100).
__global__ __launch_bounds__(512) void k_sortseg(const int* __restrict__ offs, int nseg, int* __restrict__ ids,
                                                 const int* __restrict__ conv_src, int* __restrict__ pos_of){
  __shared__ int buf[8][256];
  int w = threadIdx.x >> 6, lane = threadIdx.x & 63;
  int seg = blockIdx.x*8 + w;
  if (seg >= nseg) return;
  int s0 = offs[seg], s1 = offs[seg+1];
  int len = s1 - s0;
  if (len < 1 || len > 256) return;
  if (len == 1){
    if (lane == 0 && conv_src){
      int my = ids[s0];
      pos_of[my] = s0;
      ids[s0] = conv_src[my];
    }
    return;
  }
  int* b = buf[w];
  for (int i = lane; i < len; i += 64) b[i] = ids[s0 + i];
  for (int i = lane; i < len; i += 64){
    int my = b[i];
    int r = 0;
    for (int j = 0; j < len; j++) r += (b[j] < my);
    if (conv_src){
      pos_of[my] = s0 + r;
      ids[s0 + r] = conv_src[my];
    } else {
      ids[s0 + r] = my;
    }
  }
}

// ---------------- fused embed + A/B: x -> xe (VALU) -> h (MFMA) -> A,B (MFMA) ----------------
__global__ __launch_bounds__(512, 2) void k_embed_ab(
    const float* __restrict__ x,
    const float* __restrict__ W_e1, const float* __restrict__ b_e1,
    const float* __restrict__ W_e2, const float* __restrict__ b_e2,
    const float* __restrict__ W_e3, const float* __restrict__ b_e3,
    const float* __restrict__ W_src, const float* __restrict__ W_dst, const float* __restrict__ b_el,
    short* __restrict__ Hout, short* __restrict__ Aout, short* __restrict__ Bout, int ntiles)
{
  __shared__ short s_W[2][128][136];   // staging, reused as s_xe/s_h
  __shared__ float s_x[64][28];
  __shared__ float s_b3[128], s_bel[128];
  int tid = threadIdx.x;
  int lane = tid & 63, w = tid >> 6, lo = lane & 15, hi = lane >> 4;
  for (int idx = tid; idx < 128*128; idx += 512){
    int f = idx & 127, k = idx >> 7;
    s_W[0][f][k] = f2bf(W_e3[k*128 + f]);
    s_W[1][f][k] = f2bf(W_src[k*128 + f]);
  }
  if (tid < 128){ s_b3[tid] = b_e3[tid]; s_bel[tid] = b_el[tid]; }
  __syncthreads();
  s8v fe3[4], fsrc[4], fdst[4];
  #pragma unroll
  for (int ks = 0; ks < 4; ks++){
    fe3[ks]  = *(const s8v*)&s_W[0][w*16 + lo][ks*32 + hi*8];
    fsrc[ks] = *(const s8v*)&s_W[1][w*16 + lo][ks*32 + hi*8];
  }
  __syncthreads();
  for (int idx = tid; idx < 128*128; idx += 512){
    int f = idx & 127, k = idx >> 7;
    s_W[0][f][k] = f2bf(W_dst[k*128 + f]);
  }
  __syncthreads();
  #pragma unroll
  for (int ks = 0; ks < 4; ks++) fdst[ks] = *(const s8v*)&s_W[0][w*16 + lo][ks*32 + hi*8];

  short (*s_xe)[136] = s_W[0];
  short (*s_h)[136]  = s_W[1];

  for (int tile = blockIdx.x; tile < ntiles; tile += gridDim.x){
    int n0 = tile << 6;
    __syncthreads();
    for (int idx = tid; idx < 64*26; idx += 512){
      int nl = idx / 26, i = idx - nl*26; int n = n0 + nl;
      s_x[nl][i] = (n < kN) ? x[(size_t)n*26 + i] : 0.f;
    }
    __syncthreads();
    #pragma unroll
    for (int r = 0; r < 16; r++){
      int idx = (r << 9) + tid; int nl = idx >> 7, j = idx & 127;
      float a;
      if (j < 64){
        a = b_e1[j];
        #pragma unroll
        for (int i = 0; i < 14; i++) a += s_x[nl][i] * W_e1[i*64 + j];
      } else {
        int jj = j - 64;
        a = b_e2[jj];
        #pragma unroll
        for (int i = 0; i < 12; i++) a += s_x[nl][14 + i] * W_e2[i*64 + jj];
      }
      s_xe[nl][j] = f2bf(fmaxf(a, 0.f));
    }
    __syncthreads();
    #pragma unroll
    for (int et = 0; et < 4; et++){
      f4v acc = {0.f,0.f,0.f,0.f};
      #pragma unroll
      for (int ks = 0; ks < 4; ks++){
        s8v b = *(const s8v*)&s_xe[et*16 + lo][ks*32 + hi*8];
        acc = __builtin_amdgcn_mfma_f32_16x16x32_bf16(fe3[ks], b, acc, 0, 0, 0);
      }
      int n = n0 + et*16 + lo, f0 = w*16 + hi*4;
      s4v hv;
      #pragma unroll
      for (int j = 0; j < 4; j++) hv[j] = f2bf(fmaxf(acc[j] + s_b3[f0 + j], 0.f));
      *(s4v*)&s_h[et*16 + lo][f0] = hv;
      if (n < kN) *(s4v*)&Hout[(size_t)n*128 + f0] = hv;
    }
    __syncthreads();
    #pragma unroll
    for (int et = 0; et < 4; et++){
      f4v aA = {0.f,0.f,0.f,0.f}, aB = {0.f,0.f,0.f,0.f};
      #pragma unroll
      for (int ks = 0; ks < 4; ks++){
        s8v b = *(const s8v*)&s_h[et*16 + lo][ks*32 + hi*8];
        aA = __builtin_amdgcn_mfma_f32_16x16x32_bf16(fsrc[ks], b, aA, 0, 0, 0);
        aB = __builtin_amdgcn_mfma_f32_16x16x32_bf16(fdst[ks], b, aB, 0, 0, 0);
      }
      int n = n0 + et*16 + lo, f0 = w*16 + hi*4;
      if (n < kN){
        s4v Av, Bv;
        #pragma unroll
        for (int j = 0; j < 4; j++){ Av[j] = f2bf(aA[j] + s_bel[f0 + j]); Bv[j] = f2bf(aB[j]); }
        *(s4v*)&Aout[(size_t)n*128 + f0] = Av;
        *(s4v*)&Bout[(size_t)n*128 + f0] = Bv;
      }
    }
  }
}

// ---------------- per-edge kernel: MFMA bf16, 64 edges/tile, 8 waves (round-14 proven, UNCHANGED) ----------------
#define RO_EEMB 0        // short[64][72]  = 9216
#define RO_HE   9216     // short[64][136] = 17408 (end 26624)
#define RO_BIAS 26624    // short[64][136] = 17408 (end 44032)
#define RO_WEE  44032    // float[512]     = 2048
#define RO_BEE  46080    // float[64]      = 256
#define RO_BM   46336    // float[128]     = 512 (end 46848)
#define KE_LDS  46848
__global__ __launch_bounds__(512, 4) void k_edge(
    const short* __restrict__ Abf, const short* __restrict__ Bbf,
    const float* __restrict__ edge_attr,
    const int* __restrict__ src, const int* __restrict__ dst,
    const int* __restrict__ posp,
    const float* __restrict__ W_ee, const float* __restrict__ b_ee,
    const float* __restrict__ W_ea, const float* __restrict__ W_m,
    const float* __restrict__ b_m,
    unsigned char* __restrict__ mask_out,
    int ntiles)
{
  __shared__ __align__(16) char smem[KE_LDS];
  short (*s_eemb)[72]  = (short(*)[72])(smem + RO_EEMB);
  short (*s_he)[136]   = (short(*)[136])(smem + RO_HE);
  short (*s_bias)[136] = (short(*)[136])(smem + RO_BIAS);
  float *s_Wee = (float*)(smem + RO_WEE);
  float *s_bee = (float*)(smem + RO_BEE);
  float *s_bm  = (float*)(smem + RO_BM);

  int tid = threadIdx.x;
  const int lane = tid & 63, w = tid >> 6;
  const int lo = lane & 15, hi = lane >> 4;

  s8v a1[2], a2[4];
  {
    short (*s_stg)[72] = (short(*)[72])smem;
    for (int idx = tid; idx < 128*64; idx += 512){ int f = idx & 127, k = idx >> 7; s_stg[f][k] = f2bf(W_ea[k*128+f]); }
    __syncthreads();
    #pragma unroll
    for (int ks = 0; ks < 2; ks++) a1[ks] = *(const s8v*)&s_stg[16*w + lo][ks*32 + hi*8];
    __syncthreads();
  }
  {
    short (*s_stg)[136] = (short(*)[136])smem;
    for (int idx = tid; idx < 128*128; idx += 512){ int f = idx & 127, k = idx >> 7; s_stg[f][k] = f2bf(W_m[k*128+f]); }
    __syncthreads();
    #pragma unroll
    for (int ks = 0; ks < 4; ks++) a2[ks] = *(const s8v*)&s_stg[16*w + lo][ks*32 + hi*8];
    __syncthreads();
  }
  s_Wee[tid] = W_ee[tid];
  if (tid < 64) s_bee[tid] = b_ee[tid];
  if (tid >= 64 && tid < 192) s_bm[tid-64] = b_m[tid-64];
  __syncthreads();

  const int el8 = tid >> 3, kb = (tid & 7) << 3;
  const int p16 = (tid & 7) << 4;
  const int f0 = 16*w + hi*4;

  for (int tile = blockIdx.x; tile < ntiles; tile += gridDim.x){
    int e0 = tile << 6;
    // phase b: direct per-thread loads (edge el8), A/B gathers + eemb + bias
    {
      int eg = e0 + el8;
      int sr = src[eg], dr = dst[eg];
      float4 ea0 = *reinterpret_cast<const float4*>(&edge_attr[(size_t)eg*8]);
      float4 ea1 = *reinterpret_cast<const float4*>(&edge_attr[(size_t)eg*8 + 4]);
      int sb = sr*128 + p16, db = dr*128 + p16;
      s8v av0 = *(const s8v*)(Abf + sb);
      s8v av1 = *(const s8v*)(Abf + sb + 8);
      s8v bv0 = *(const s8v*)(Bbf + db);
      s8v bv1 = *(const s8v*)(Bbf + db + 8);
      float eav[8] = {ea0.x, ea0.y, ea0.z, ea0.w, ea1.x, ea1.y, ea1.z, ea1.w};
      float ee_[8];
      #pragma unroll
      for (int j = 0; j < 8; j++){
        float acc = s_bee[kb + j];
        #pragma unroll
        for (int i = 0; i < 8; i++) acc += eav[i] * s_Wee[i*64 + kb + j];
        ee_[j] = fmaxf(acc, 0.f);
      }
      s8v ep;
      #pragma unroll
      for (int j = 0; j < 8; j++) ep[j] = f2bf(ee_[j]);
      *(s8v*)&s_eemb[el8][kb] = ep;
      s8v b0, b1;
      #pragma unroll
      for (int q = 0; q < 8; q++){
        b0[q] = f2bf(bf2f(av0[q]) + bf2f(bv0[q]));
        b1[q] = f2bf(bf2f(av1[q]) + bf2f(bv1[q]));
      }
      *(s8v*)&s_bias[el8][p16]     = b0;
      *(s8v*)&s_bias[el8][p16 + 8] = b1;
    }
    __syncthreads();
    // phase c: GEMM1 (K=64), acc init = bias
    #pragma unroll
    for (int et = 0; et < 4; et++){
      int e = et*16 + lo;
      s4v bb = *(const s4v*)&s_bias[e][f0];
      f4v acc;
      #pragma unroll
      for (int j = 0; j < 4; j++) acc[j] = bf2f(bb[j]);
      #pragma unroll
      for (int ks = 0; ks < 2; ks++){
        s8v bfrag = *(const s8v*)&s_eemb[e][ks*32 + hi*8];
        acc = __builtin_amdgcn_mfma_f32_16x16x32_bf16(a1[ks], bfrag, acc, 0, 0, 0);
      }
      s4v hw;
      #pragma unroll
      for (int j = 0; j < 4; j++) hw[j] = f2bf(fmaxf(acc[j], 0.f));
      *(s4v*)&s_he[e][f0] = hw;
    }
    __syncthreads();
    // phase d: GEMM2 (K=128) -> fast-sigmoid -> packed u8 store
    #pragma unroll
    for (int et = 0; et < 4; et++){
      int e = et*16 + lo;
      int pe = posp[e0 + e];
      f4v acc = {0.f, 0.f, 0.f, 0.f};
      #pragma unroll
      for (int ks = 0; ks < 4; ks++){
        s8v bfrag = *(const s8v*)&s_he[e][ks*32 + hi*8];
        acc = __builtin_amdgcn_mfma_f32_16x16x32_bf16(a2[ks], bfrag, acc, 0, 0, 0);
      }
      unsigned pk = 0;
      #pragma unroll
      for (int j = 0; j < 4; j++){
        float ex = __expf(-(acc[j] + s_bm[f0 + j]));
        float m255 = __fdividef(255.f, 1.f + ex);
        pk |= (__float2uint_rn(m255) & 255u) << (j*8);
      }
      *reinterpret_cast<unsigned*>(&mask_out[(size_t)pe*128 + f0]) = pk;
    }
    __syncthreads();
  }
}

// ---------------- fused conv layer: gather-aggregate + (agg@Wn + h@Wr) MFMA ----------------
// (512,4): arch cap 64, proven no-spill (round 17: fixed silent spill, -42 µs).
__global__ __launch_bounds__(512, 4) void k_conv(
    const short* __restrict__ Hbf,
    const unsigned char* __restrict__ mask8,
    const int* __restrict__ src_sorted, const int* __restrict__ offs,
    const float* __restrict__ Wn, const float* __restrict__ Wr, const float* __restrict__ bc,
    short* __restrict__ Hout, float* __restrict__ Pout, int ntiles)
{
  __shared__ short s_buf[128][136];
  __shared__ float s_bc[128];
  int tid = threadIdx.x;
  int lane = tid & 63, w = tid >> 6, lo = lane & 15, hi = lane >> 4;
  s8v fn[4], fr[4];
  for (int idx = tid; idx < 128*128; idx += 512){
    int f = idx & 127, k = idx >> 7;
    s_buf[f][k] = f2bf(Wn[k*128 + f]);
  }
  if (tid < 128) s_bc[tid] = bc[tid];
  __syncthreads();
  #pragma unroll
  for (int ks = 0; ks < 4; ks++) fn[ks] = *(const s8v*)&s_buf[w*16 + lo][ks*32 + hi*8];
  __syncthreads();
  for (int idx = tid; idx < 128*128; idx += 512){
    int f = idx & 127, k = idx >> 7;
    s_buf[f][k] = f2bf(Wr[k*128 + f]);
  }
  __syncthreads();
  #pragma unroll
  for (int ks = 0; ks < 4; ks++) fr[ks] = *(const s8v*)&s_buf[w*16 + lo][ks*32 + hi*8];

  short (*s_agg)[136] = s_buf;        // rows 0..63
  short (*s_h)[136]   = s_buf + 64;   // rows 64..127
  const int nl8 = tid >> 3, p16 = (tid & 7) << 4;

  for (int tile = blockIdx.x; tile < ntiles; tile += gridDim.x){
    int n0 = tile << 6;
    __syncthreads();
    int n = n0 + nl8;
    {
      s8v h0 = {0,0,0,0,0,0,0,0}, h1 = {0,0,0,0,0,0,0,0};
      if (n < kN){
        h0 = *(const s8v*)&Hbf[(size_t)n*128 + p16];
        h1 = *(const s8v*)&Hbf[(size_t)n*128 + p16 + 8];
      }
      *(s8v*)&s_h[nl8][p16] = h0;
      *(s8v*)&s_h[nl8][p16 + 8] = h1;
    }
    float acc[16];
    #pragma unroll
    for (int q = 0; q < 16; q++) acc[q] = 0.f;
    int s0 = 0, s1 = 0;
    if (n < kN){ s0 = offs[n]; s1 = offs[n+1]; }
    int4 mv_c = {0,0,0,0}; s8v g0_c = {0,0,0,0,0,0,0,0}, g1_c = {0,0,0,0,0,0,0,0};
    if (s0 < s1){
      int sv = src_sorted[s0];
      mv_c = *reinterpret_cast<const int4*>(&mask8[(size_t)s0*128 + p16]);
      g0_c = *(const s8v*)&Hbf[(size_t)sv*128 + p16];
      g1_c = *(const s8v*)&Hbf[(size_t)sv*128 + p16 + 8];
    }
    for (int i = s0; i < s1; i++){
      int4 mv = mv_c; s8v g0 = g0_c, g1 = g1_c;
      int nx = (i + 1 < s1) ? i + 1 : i;
      int svn = src_sorted[nx];
      mv_c = *reinterpret_cast<const int4*>(&mask8[(size_t)nx*128 + p16]);
      g0_c = *(const s8v*)&Hbf[(size_t)svn*128 + p16];
      g1_c = *(const s8v*)&Hbf[(size_t)svn*128 + p16 + 8];
      unsigned mw[4] = {(unsigned)mv.x, (unsigned)mv.y, (unsigned)mv.z, (unsigned)mv.w};
      float mf16[16];
      #pragma unroll
      for (int d = 0; d < 4; d++){
        mf16[d*4+0] = (float)( mw[d]        & 255u);
        mf16[d*4+1] = (float)((mw[d] >>  8) & 255u);
        mf16[d*4+2] = (float)((mw[d] >> 16) & 255u);
        mf16[d*4+3] = (float)( mw[d] >> 24       );
      }
      #pragma unroll
      for (int q = 0; q < 8; q++) acc[q]     += bf2f(g0[q]) * mf16[q];
      #pragma unroll
      for (int q = 0; q < 8; q++) acc[8 + q] += bf2f(g1[q]) * mf16[8 + q];
    }
    float inv = (1.f/255.f) * __fdividef(1.f, fmaxf((float)(s1 - s0), 1.f));
    {
      s8v a0, a1;
      #pragma unroll
      for (int q = 0; q < 8; q++){ a0[q] = f2bf(acc[q]*inv); a1[q] = f2bf(acc[8+q]*inv); }
      *(s8v*)&s_agg[nl8][p16] = a0;
      *(s8v*)&s_agg[nl8][p16 + 8] = a1;
    }
    __syncthreads();
    #pragma unroll
    for (int et = 0; et < 4; et++){
      f4v ac = {0.f,0.f,0.f,0.f};
      #pragma unroll
      for (int ks = 0; ks < 4; ks++){
        s8v bA = *(const s8v*)&s_agg[et*16 + lo][ks*32 + hi*8];
        ac = __builtin_amdgcn_mfma_f32_16x16x32_bf16(fn[ks], bA, ac, 0, 0, 0);
        s8v bH = *(const s8v*)&s_h[et*16 + lo][ks*32 + hi*8];
        ac = __builtin_amdgcn_mfma_f32_16x16x32_bf16(fr[ks], bH, ac, 0, 0, 0);
      }
      int nn = n0 + et*16 + lo, f0 = w*16 + hi*4;
      if (nn < kN){
        s4v hv; float4 pv;
        float v0 = fmaxf(ac[0] + s_bc[f0 + 0], 0.f);
        float v1 = fmaxf(ac[1] + s_bc[f0 + 1], 0.f);
        float v2 = fmaxf(ac[2] + s_bc[f0 + 2], 0.f);
        float v3 = fmaxf(ac[3] + s_bc[f0 + 3], 0.f);
        hv[0] = f2bf(v0); hv[1] = f2bf(v1); hv[2] = f2bf(v2); hv[3] = f2bf(v3);
        pv.x = v0; pv.y = v1; pv.z = v2; pv.w = v3;
        if (Hout) *(s4v*)&Hout[(size_t)nn*128 + f0] = hv;
        *reinterpret_cast<float4*>(&Pout[(size_t)nn*128 + f0]) = pv;
      }
    }
  }
}

// ---------------- final: community gather-pool (mean+max, no atomics) + MLP ----------------
__global__ __launch_bounds__(128) void k_final(
    const float* __restrict__ p1f, const float* __restrict__ p2f,
    const int* __restrict__ node_by_comm, const int* __restrict__ coffs,
    const float* __restrict__ W_l1, const float* __restrict__ b_l1,
    const float* __restrict__ W_l2, const float* __restrict__ b_l2,
    float* __restrict__ out)
{
  __shared__ float p[256];
  __shared__ float red[2];
  int c = blockIdx.x, t = threadIdx.x;
  int c0 = coffs[c], c1 = coffs[c+1];
  float s = 0.f, m1 = 0.f, m2 = 0.f;
  float v1_c = 0.f, v2_c = 0.f;
  if (c0 < c1){
    int n = node_by_comm[c0];
    v1_c = p1f[(size_t)n*128 + t];
    v2_c = p2f[(size_t)n*128 + t];
  }
  for (int i = c0; i < c1; i++){
    float v1 = v1_c, v2 = v2_c;
    if (i + 1 < c1){
      int nn = node_by_comm[i + 1];
      v1_c = p1f[(size_t)nn*128 + t];
      v2_c = p2f[(size_t)nn*128 + t];
    }
    s += v1 + v2;
    m1 = fmaxf(m1, v1);
    m2 = fmaxf(m2, v2);
  }
  float inv = 1.f / fmaxf((float)(c1 - c0), 1.f);
  p[t]       = s * inv;
  p[128 + t] = m1 + m2;
  __syncthreads();
  float acc = b_l1[t];
  for (int g = 0; g < 256; g++) acc += p[g]*W_l1[g*128+t];
  float hv = fmaxf(acc, 0.f) * W_l2[t];
  #pragma unroll
  for (int off = 32; off > 0; off >>= 1) hv += __shfl_down(hv, off);
  if ((t & 63) == 0) red[t>>6] = hv;
  __syncthreads();
  if (t == 0) out[c] = red[0] + red[1] + b_l2[0];
}

// diagnostic: surface ws_size through the absmax if workspace is too small
__global__ void k_diag(float* out, float v){
  int i = blockIdx.x*256 + threadIdx.x;
  if (i < kC) out[i] = v;
}

extern "C" void kernel_launch(void* const* d_in, const int* in_sizes, int n_in,
                              void* d_out, int out_size, void* d_ws, size_t ws_size,
                              hipStream_t stream)
{
  const float* x    = (const float*)d_in[0];
  const float* ea   = (const float*)d_in[1];
  const float* W_ee = (const float*)d_in[2];  const float* b_ee = (const float*)d_in[3];
  const float* W_e1 = (const float*)d_in[4];  const float* b_e1 = (const float*)d_in[5];
  const float* W_e2 = (const float*)d_in[6];  const float* b_e2 = (const float*)d_in[7];
  const float* W_e3 = (const float*)d_in[8];  const float* b_e3 = (const float*)d_in[9];
  const float* W_src= (const float*)d_in[10]; const float* W_dst= (const float*)d_in[11];
  const float* W_ea = (const float*)d_in[12]; const float* b_el = (const float*)d_in[13];
  const float* W_m  = (const float*)d_in[14]; const float* b_m  = (const float*)d_in[15];
  const float* W_n1 = (const float*)d_in[16]; const float* W_r1 = (const float*)d_in[17]; const float* b_c1 = (const float*)d_in[18];
  const float* W_n2 = (const float*)d_in[19]; const float* W_r2 = (const float*)d_in[20]; const float* b_c2 = (const float*)d_in[21];
  const float* W_l1 = (const float*)d_in[22]; const float* b_l1 = (const float*)d_in[23];
  const float* W_l2 = (const float*)d_in[24]; const float* b_l2 = (const float*)d_in[25];
  const int* eidx   = (const int*)d_in[26];
  const int* srcp   = eidx;
  const int* dstp   = eidx + kE;
  const int* community = (const int*)d_in[27];
  float* out = (float*)d_out;

  char* ws = (char*)d_ws;
  size_t off = 0;
  auto take = [&](size_t bytes)->char*{
    char* p = ws + off;
    off += (bytes + 511) & ~(size_t)511;
    return p;
  };
  const size_t NB2 = (size_t)kN*128*2;   // bf16 node buffer
  const size_t NB4 = (size_t)kN*128*4;   // fp32 node buffer
  short* hbuf  = (short*)take(NB2);
  short* h1buf = (short*)take(NB2);
  short* Abf16 = (short*)take(NB2);
  short* Bbf16 = (short*)take(NB2);
  float* p1f   = (float*)take(NB4);
  float* p2f   = (float*)take(NB4);
  char* z0 = ws + off;
  int* deg     = (int*)take((size_t)kN*4);
  int* cursor  = (int*)take((size_t)kN*4);
  int* ccnt    = (int*)take((size_t)kC*4);
  int* ccursor = (int*)take((size_t)kC*4);
  size_t zbytes = (size_t)((ws + off) - z0);
  int* offs    = (int*)take((size_t)(kN+1)*4);
  int* coffs   = (int*)take((size_t)(kC+1)*4);
  int* node_by_comm = (int*)take((size_t)kN*4);
  int* bsum    = (int*)take(128);
  unsigned char* mask8 = (unsigned char*)take((size_t)kE*128);
  int* src_sorted  = (int*)take((size_t)kE*4);   // holds eids until sortseg converts to src
  int* pos_of_edge = (int*)take((size_t)kE*4);
  size_t need = off;

  const int ntE   = (kE + 63) / 64;
  const int ntN64 = (kN + 63) / 64;
  const int nScanBlk = (kN + 4095) / 4096;   // 13

  if (ws_size >= need){
    hipMemsetAsync(z0, 0, zbytes, stream);
    k_hist    <<<(kE+255)/256, 256, 0, stream>>>(dstp, deg, community, ccnt);
    k_embed_ab<<<512, 512, 0, stream>>>(x, W_e1,b_e1, W_e2,b_e2, W_e3,b_e3,
                                        W_src, W_dst, b_el, hbuf, Abf16, Bbf16, ntN64);
    k_scan1   <<<nScanBlk, 1024, 0, stream>>>(deg, offs, bsum);
    k_scan2   <<<(kN+1023)/1024, 1024, 0, stream>>>(offs, bsum, nScanBlk);
    k_scan_c  <<<1, 512, 0, stream>>>(ccnt, coffs);
    k_place   <<<(kE+255)/256, 256, 0, stream>>>(dstp, offs, cursor, src_sorted, kE);
    k_place   <<<(kN+255)/256, 256, 0, stream>>>(community, coffs, ccursor, node_by_comm, kN);
    k_sortseg <<<(kN+7)/8, 512, 0, stream>>>(offs, kN, src_sorted, srcp, pos_of_edge);
    k_sortseg <<<(kC+7)/8, 512, 0, stream>>>(coffs, kC, node_by_comm, nullptr, nullptr);
    k_edge    <<<512, 512, 0, stream>>>(Abf16, Bbf16, ea, srcp, dstp, pos_of_edge,
                                        W_ee, b_ee, W_ea, W_m, b_m, mask8, ntE);
    k_conv    <<<ntN64, 512, 0, stream>>>(hbuf, mask8, src_sorted, offs,
                                          W_n1, W_r1, b_c1, h1buf, p1f, ntN64);
    k_conv    <<<ntN64, 512, 0, stream>>>(h1buf, mask8, src_sorted, offs,
                                          W_n2, W_r2, b_c2, nullptr, p2f, ntN64);
    k_final   <<<kC, 128, 0, stream>>>(p1f, p2f, node_by_comm, coffs,
                                       W_l1, b_l1, W_l2, b_l2, out);
  } else {
    k_diag<<<8, 256, 0, stream>>>(out, (float)(ws_size >> 20));
  }
}